// Round 12
// baseline (1602.530 us; speedup 1.0000x reference)
//
#include <hip/hip_runtime.h>
#include <hip/hip_fp16.h>
#include <math.h>

#define HDIM 128
typedef unsigned short u16;
typedef __attribute__((ext_vector_type(8))) short bf16x8;
typedef __attribute__((ext_vector_type(4))) float f32x4;

__device__ __forceinline__ u16 f2bf(float x) {
    unsigned u = __float_as_uint(x);
    u = (u + 0x7FFFu + ((u >> 16) & 1u)) >> 16;
    return (u16)u;
}
__device__ __forceinline__ float bf2f(u16 h) {
    return __uint_as_float(((unsigned)h) << 16);
}
__device__ __forceinline__ bf16x8 ld8(const u16* p) {
    return *reinterpret_cast<const bf16x8*>(p);
}
__device__ __forceinline__ void split8(const float* v, bf16x8& hi, bf16x8& lo) {
#pragma unroll
    for (int j = 0; j < 8; ++j) {
        unsigned u = __float_as_uint(v[j]);
        unsigned h = (u + 0x7FFFu + ((u >> 16) & 1u)) >> 16;
        float rem = v[j] - __uint_as_float(h << 16);
        hi[j] = (short)h;
        lo[j] = (short)(__float_as_uint(rem) >> 16);
    }
}
__device__ __forceinline__ float2 up2(unsigned u) {
    __half2 h = *reinterpret_cast<__half2*>(&u);
    float2 f; f.x = __low2float(h); f.y = __high2float(h); return f;
}
__device__ __forceinline__ u16 f2h(float x) {
    __half t = __float2half(x);
    return *reinterpret_cast<u16*>(&t);
}
__device__ __forceinline__ void acc_u4(float* a, uint4 u, float w) {
    float2 v0 = up2(u.x), v1 = up2(u.y), v2 = up2(u.z), v3 = up2(u.w);
    a[0] = fmaf(w, v0.x, a[0]); a[1] = fmaf(w, v0.y, a[1]);
    a[2] = fmaf(w, v1.x, a[2]); a[3] = fmaf(w, v1.y, a[3]);
    a[4] = fmaf(w, v2.x, a[4]); a[5] = fmaf(w, v2.y, a[5]);
    a[6] = fmaf(w, v3.x, a[6]); a[7] = fmaf(w, v3.y, a[7]);
}
#define MFMA(acc, a, b) acc = __builtin_amdgcn_mfma_f32_16x16x32_bf16(a, b, acc, 0, 0, 0)

// ---------------- weight prep -----------------------------------------------
// Wfull[s][c][k] = dot(Ws[s][k][:], Wih[c][:])  (gi = (hagg@Ws)@Wih^T), hi/lo
__global__ __launch_bounds__(256) void prep_wfull(const float* __restrict__ Ws,
                                                  const float* __restrict__ Wih,
                                                  u16* __restrict__ hi, u16* __restrict__ lo) {
    int s = blockIdx.y;
    int idx = blockIdx.x * 256 + threadIdx.x;   // [0, 49152)
    int c2 = idx >> 7, r = idx & 127;
    const float* wr = Ws + (size_t)s * 16384 + (size_t)r * 128;
    const float* wc = Wih + (size_t)c2 * 128;
    float acc = 0.f;
#pragma unroll 8
    for (int k = 0; k < 128; k += 4) {
        float4 a = *reinterpret_cast<const float4*>(wr + k);
        float4 b = *reinterpret_cast<const float4*>(wc + k);
        acc += a.x * b.x + a.y * b.y + a.z * b.z + a.w * b.w;
    }
    size_t o = (size_t)s * 49152 + idx;
    u16 h = f2bf(acc);
    hi[o] = h; lo[o] = f2bf(acc - bf2f(h));
}

__global__ __launch_bounds__(256) void prep_split(const float* __restrict__ W,
                                                  u16* __restrict__ hi, u16* __restrict__ lo, int n) {
    int i = blockIdx.x * 256 + threadIdx.x;
    if (i < n) { float v = W[i]; u16 h = f2bf(v); hi[i] = h; lo[i] = f2bf(v - bf2f(h)); }
}

// WinT[r][c] = W_in[c][r], [128][64]
__global__ __launch_bounds__(256) void prep_win(const float* __restrict__ W,
                                                u16* __restrict__ hi, u16* __restrict__ lo) {
    int idx = blockIdx.x * 256 + threadIdx.x;        // 0..8191
    int r = idx >> 6, c = idx & 63;
    float v = W[(size_t)c * 128 + r];
    u16 h = f2bf(v);
    hi[idx] = h; lo[idx] = f2bf(v - bf2f(h));
}

// ---------------- embed: Hh = fp16(tanh(X @ Win)), fp32 X read directly -----
__global__ __launch_bounds__(256) void embed_k(const float* __restrict__ X0, const float* __restrict__ X1,
                                               const u16* __restrict__ Bhi0, const u16* __restrict__ Blo0,
                                               const u16* __restrict__ Bhi1, const u16* __restrict__ Blo1,
                                               u16* __restrict__ Hh0, u16* __restrict__ Hh1, int Nn) {
    const int by = blockIdx.y;
    const float* X = by ? X1 : X0;
    const u16* Bhi = by ? Bhi1 : Bhi0;  const u16* Blo = by ? Blo1 : Blo0;
    u16* Hh = by ? Hh1 : Hh0;
    const int tid = threadIdx.x, wave = tid >> 6, lane = tid & 63;
    const int row0 = blockIdx.x * 32, cs = wave * 32;
    const int lr = lane & 15, lk = (lane >> 4) * 8;
    f32x4 acc[2][2];
#pragma unroll
    for (int i = 0; i < 2; ++i)
#pragma unroll
        for (int j = 0; j < 2; ++j) acc[i][j] = (f32x4)0.f;
#pragma unroll
    for (int kc = 0; kc < 2; ++kc) {
        float xv[8];
        bf16x8 ah0, al0, ah1, al1;
        const int r0i = row0 + lr;
        if (r0i < Nn) {
            const float* xp = X + (size_t)r0i * 64 + kc * 32 + lk;
            *reinterpret_cast<float4*>(&xv[0]) = *reinterpret_cast<const float4*>(xp);
            *reinterpret_cast<float4*>(&xv[4]) = *reinterpret_cast<const float4*>(xp + 4);
        } else {
#pragma unroll
            for (int j = 0; j < 8; ++j) xv[j] = 0.f;
        }
        split8(xv, ah0, al0);
        const int r1i = row0 + 16 + lr;
        if (r1i < Nn) {
            const float* xp = X + (size_t)r1i * 64 + kc * 32 + lk;
            *reinterpret_cast<float4*>(&xv[0]) = *reinterpret_cast<const float4*>(xp);
            *reinterpret_cast<float4*>(&xv[4]) = *reinterpret_cast<const float4*>(xp + 4);
        } else {
#pragma unroll
            for (int j = 0; j < 8; ++j) xv[j] = 0.f;
        }
        split8(xv, ah1, al1);
#pragma unroll
        for (int cf = 0; cf < 2; ++cf) {
            const size_t bo = (size_t)(cs + cf * 16 + lr) * 64 + kc * 32 + lk;
            bf16x8 bh = ld8(Bhi + bo), bl = ld8(Blo + bo);
            MFMA(acc[0][cf], ah0, bh); MFMA(acc[0][cf], ah0, bl); MFMA(acc[0][cf], al0, bh);
            MFMA(acc[1][cf], ah1, bh); MFMA(acc[1][cf], ah1, bl); MFMA(acc[1][cf], al1, bh);
        }
    }
#pragma unroll
    for (int rf = 0; rf < 2; ++rf)
#pragma unroll
        for (int cf = 0; cf < 2; ++cf)
#pragma unroll
            for (int rg = 0; rg < 4; ++rg) {
                int row = row0 + rf * 16 + (lane >> 4) * 4 + rg;
                int col = cs + cf * 16 + lr;
                Hh[(size_t)row * HDIM + col] = f2h(tanhf(acc[rf][cf][rg]));
            }
}

// ---------------- fused step: 4-edges-per-load gather, GRU GEMM; 2 graphs ---
// 512 threads = 8 waves; block covers 32 node-rows of graph blockIdx.y.
// phase 1: wave w gathers nodes w*4..w*4+3; each 16-lane group loads one
//          256B row as uint4 (4 edges per wave-instruction, 1KB).
// phase 2: wave w computes cols w*16..w*16+16 of all 6 gate strips via MFMA.
__global__ __launch_bounds__(512, 8) void step_k(const u16* __restrict__ Hh0, const u16* __restrict__ Hh1,
                                                 const int* __restrict__ ro0, const int* __restrict__ ro1,
                                                 const int* __restrict__ ss0, const int* __restrict__ ss1,
                                                 const u16* __restrict__ Wf0h, const u16* __restrict__ Wf0l,
                                                 const u16* __restrict__ Wf1h, const u16* __restrict__ Wf1l,
                                                 const u16* __restrict__ Wh0h, const u16* __restrict__ Wh0l,
                                                 const u16* __restrict__ Wh1h, const u16* __restrict__ Wh1l,
                                                 const float* __restrict__ bi0, const float* __restrict__ bh0,
                                                 const float* __restrict__ bi1, const float* __restrict__ bh1,
                                                 u16* __restrict__ Hn0, u16* __restrict__ Hn1, int Nn) {
    __shared__ u16 agh[32][136];
    __shared__ u16 agl[32][136];
    __shared__ u16 hhh[32][136];
    __shared__ u16 hhl[32][136];
    __shared__ int eidx[1024];
    const int by = blockIdx.y;
    const u16* Hh = by ? Hh1 : Hh0;
    const int* row_off = by ? ro1 : ro0;
    const int* ssrc = by ? ss1 : ss0;
    const int tid = threadIdx.x, wave = tid >> 6, lane = tid & 63;
    const int row0 = blockIdx.x * 32;
    const int g16 = lane >> 4, l16 = lane & 15;

    // ---- phase 0: stage edge indices into LDS ----
    const int rowEnd = (row0 + 32 < Nn) ? row0 + 32 : Nn;
    const int eLo = row_off[row0];
    const int nE = row_off[rowEnd] - eLo;
    for (int i = tid; i < nE && i < 1024; i += 512) eidx[i] = ssrc[eLo + i];
    __syncthreads();

    // ---- phase 1: gather neighbor-sum, 4 edges per load instruction ----
#pragma unroll
    for (int q = 0; q < 4; ++q) {
        const int nl = wave * 4 + q;
        const int node = row0 + nl;
        float a8[8];
#pragma unroll
        for (int j = 0; j < 8; ++j) a8[j] = 0.f;
        if (node < Nn) {
            const int lo = row_off[node] - eLo;
            const int hi = row_off[node + 1] - eLo;
            if (hi > lo) {
                // masked 16-edge burst (one latency window for ~89% of nodes)
                uint4 u[4]; float w[4];
#pragma unroll
                for (int b = 0; b < 4; ++b) {
                    const int p = lo + b * 4 + g16;
                    const bool val = p < hi;
                    const int ps = val ? p : lo;
                    const int idx = (ps < 1024) ? eidx[ps] : ssrc[eLo + ps];
                    u[b] = *reinterpret_cast<const uint4*>(Hh + (size_t)idx * HDIM + l16 * 8);
                    w[b] = val ? 1.f : 0.f;
                }
#pragma unroll
                for (int b = 0; b < 4; ++b) acc_u4(a8, u[b], w[b]);
                // overflow (deg > 16), 4 edges per iteration
                for (int i = lo + 16; i < hi; i += 4) {
                    const int p = i + g16;
                    const bool val = p < hi;
                    const int ps = val ? p : lo;
                    const int idx = (ps < 1024) ? eidx[ps] : ssrc[eLo + ps];
                    uint4 uu = *reinterpret_cast<const uint4*>(Hh + (size_t)idx * HDIM + l16 * 8);
                    acc_u4(a8, uu, val ? 1.f : 0.f);
                }
            }
        }
        // cross-group reduce: each lane ends with full sums for its 8 cols
#pragma unroll
        for (int j = 0; j < 8; ++j) {
            a8[j] += __shfl_xor(a8[j], 16);
            a8[j] += __shfl_xor(a8[j], 32);
        }
        if (g16 == 0) {
            bf16x8 h8, l8;
            split8(a8, h8, l8);
            *reinterpret_cast<bf16x8*>(&agh[nl][l16 * 8]) = h8;
            *reinterpret_cast<bf16x8*>(&agl[nl][l16 * 8]) = l8;
        }
    }

    // ---- phase 1c: stage own h rows (fp16 exact), split -> bf16 hi/lo LDS ----
    {
        const int r = tid >> 4, c0 = (tid & 15) * 8;
        float v[8];
        const int row = row0 + r;
        if (row < Nn) {
            const u16* hp = Hh + (size_t)row * HDIM + c0;
#pragma unroll
            for (int j = 0; j < 4; ++j) {
                float2 f = up2(*reinterpret_cast<const unsigned*>(hp + j * 2));
                v[j * 2] = f.x; v[j * 2 + 1] = f.y;
            }
        } else {
#pragma unroll
            for (int j = 0; j < 8; ++j) v[j] = 0.f;
        }
        bf16x8 hi, lo;
        split8(v, hi, lo);
        *reinterpret_cast<bf16x8*>(&hhh[r][c0]) = hi;
        *reinterpret_cast<bf16x8*>(&hhl[r][c0]) = lo;
    }
    __syncthreads();

    // ---- phase 2: GEMM + gates; wave owns 16 cols (cs), 32 rows ----
    const u16* Wfhi = by ? Wf1h : Wf0h;  const u16* Wflo = by ? Wf1l : Wf0l;
    const u16* Whhi = by ? Wh1h : Wh0h;  const u16* Whlo = by ? Wh1l : Wh0l;
    const float* bih = by ? bi1 : bi0;   const float* bhh = by ? bh1 : bh0;
    u16* Hnh = by ? Hn1 : Hn0;
    const int lr = lane & 15, lk = (lane >> 4) * 8, cs = wave * 16;
    f32x4 accI[2][3], accH[2][3];
#pragma unroll
    for (int rf = 0; rf < 2; ++rf)
#pragma unroll
        for (int g = 0; g < 3; ++g) { accI[rf][g] = (f32x4)0.f; accH[rf][g] = (f32x4)0.f; }
#pragma unroll
    for (int kc = 0; kc < 4; ++kc) {
        bf16x8 ga[2], gl[2], ha[2], hl[2];
#pragma unroll
        for (int rf = 0; rf < 2; ++rf) {
            const int rr = rf * 16 + lr, cc = kc * 32 + lk;
            ga[rf] = *reinterpret_cast<const bf16x8*>(&agh[rr][cc]);
            gl[rf] = *reinterpret_cast<const bf16x8*>(&agl[rr][cc]);
            ha[rf] = *reinterpret_cast<const bf16x8*>(&hhh[rr][cc]);
            hl[rf] = *reinterpret_cast<const bf16x8*>(&hhl[rr][cc]);
        }
#pragma unroll
        for (int g = 0; g < 3; ++g) {
            const size_t bo = (size_t)(g * 128 + cs + lr) * HDIM + kc * 32 + lk;
            bf16x8 fh = ld8(Wfhi + bo), fl = ld8(Wflo + bo);
            bf16x8 wh = ld8(Whhi + bo), wl = ld8(Whlo + bo);
#pragma unroll
            for (int rf = 0; rf < 2; ++rf) {
                MFMA(accI[rf][g], ga[rf], fh); MFMA(accI[rf][g], ga[rf], fl); MFMA(accI[rf][g], gl[rf], fh);
                MFMA(accH[rf][g], ha[rf], wh); MFMA(accH[rf][g], ha[rf], wl); MFMA(accH[rf][g], hl[rf], wh);
            }
        }
    }
    const int c = cs + lr;
    const float bir = bih[c], biz = bih[128 + c], bin = bih[256 + c];
    const float bhr = bhh[c], bhz = bhh[128 + c], bhn = bhh[256 + c];
#pragma unroll
    for (int rf = 0; rf < 2; ++rf)
#pragma unroll
        for (int rg = 0; rg < 4; ++rg) {
            const int rl = rf * 16 + (lane >> 4) * 4 + rg;
            const int row = row0 + rl;
            float gir = accI[rf][0][rg] + bir;
            float giz = accI[rf][1][rg] + biz;
            float gin = accI[rf][2][rg] + bin;
            float ghr = accH[rf][0][rg] + bhr;
            float ghz = accH[rf][1][rg] + bhz;
            float ghn = accH[rf][2][rg] + bhn;
            float r = 1.f / (1.f + expf(-(gir + ghr)));
            float z = 1.f / (1.f + expf(-(giz + ghz)));
            float nn = tanhf(gin + r * ghn);
            float hold = bf2f(hhh[rl][c]) + bf2f(hhl[rl][c]);
            float hn = (1.f - z) * nn + z * hold;
            if (row < Nn) Hnh[(size_t)row * HDIM + c] = f2h(hn);
        }
}

// ---------------- CSR build (both graphs via blockIdx.y) --------------------
__global__ void zero_int2(int* p0, int* p1, int n) {
    int i = blockIdx.x * 256 + threadIdx.x;
    int* p = blockIdx.y ? p1 : p0;
    if (i < n) p[i] = 0;
}

__global__ void hist_k2(const int* __restrict__ d0, const int* __restrict__ d1,
                        int* __restrict__ c0, int* __restrict__ c1, int E) {
    int e = blockIdx.x * 256 + threadIdx.x;
    const int* dst = blockIdx.y ? d1 : d0;
    int* cnt = blockIdx.y ? c1 : c0;
    if (e < E) atomicAdd(&cnt[dst[e]], 1);
}

// parallel scan, 3 phases. A: per-block (1024 elems) partial scan + block total.
__global__ __launch_bounds__(256) void scan_part(const int* __restrict__ c0, const int* __restrict__ c1,
                                                 int* __restrict__ r0, int* __restrict__ r1,
                                                 int* __restrict__ bt0, int* __restrict__ bt1, int n) {
    const int* cnt = blockIdx.y ? c1 : c0;
    int* ro = blockIdx.y ? r1 : r0;
    int* bt = blockIdx.y ? bt1 : bt0;
    __shared__ int wsum[4];
    const int tid = threadIdx.x, lane = tid & 63, wv = tid >> 6;
    const int i0 = blockIdx.x * 1024 + tid * 4;
    int v[4];
#pragma unroll
    for (int j = 0; j < 4; ++j) v[j] = (i0 + j < n) ? cnt[i0 + j] : 0;
    int s = v[0] + v[1] + v[2] + v[3];
    int x = s;
#pragma unroll
    for (int off = 1; off < 64; off <<= 1) { int t = __shfl_up(x, off); if (lane >= off) x += t; }
    if (lane == 63) wsum[wv] = x;
    __syncthreads();
    int wbase = 0;
#pragma unroll
    for (int w = 0; w < 4; ++w) wbase += (w < wv) ? wsum[w] : 0;
    int run = wbase + x - s;
#pragma unroll
    for (int j = 0; j < 4; ++j) { if (i0 + j < n) ro[i0 + j] = run; run += v[j]; }
    if (tid == 255) bt[blockIdx.x] = wbase + x;
}

// B: exclusive-scan the block totals (nb <= 64); bt[nb] = grand total.
__global__ void scan_tops(int* __restrict__ bt0, int* __restrict__ bt1, int nb) {
    int* bt = blockIdx.x ? bt1 : bt0;
    const int lane = threadIdx.x;   // 64 threads
    int v = (lane < nb) ? bt[lane] : 0;
    int x = v;
#pragma unroll
    for (int off = 1; off < 64; off <<= 1) { int t = __shfl_up(x, off); if (lane >= off) x += t; }
    if (lane < nb) bt[lane] = x - v;
    if (lane == 63) bt[nb] = x;
}

// C: add block offsets; write cursor copy and row_off[n].
__global__ void scan_fix(int* __restrict__ r0, int* __restrict__ r1,
                         const int* __restrict__ bt0, const int* __restrict__ bt1,
                         int* __restrict__ cur0, int* __restrict__ cur1, int n, int nb) {
    const int i = blockIdx.x * 256 + threadIdx.x;
    int* ro = blockIdx.y ? r1 : r0;
    const int* bt = blockIdx.y ? bt1 : bt0;
    int* cur = blockIdx.y ? cur1 : cur0;
    if (i < n) {
        int val = ro[i] + bt[i >> 10];
        ro[i] = val;
        cur[i] = val;
    } else if (i == n) {
        ro[n] = bt[nb];
    }
}

__global__ void scatter_k2(const int* __restrict__ s0, const int* __restrict__ d0,
                           const int* __restrict__ s1, const int* __restrict__ d1,
                           int* __restrict__ c0, int* __restrict__ c1,
                           int* __restrict__ o0, int* __restrict__ o1, int E) {
    int e = blockIdx.x * 256 + threadIdx.x;
    const int* src = blockIdx.y ? s1 : s0;
    const int* dst = blockIdx.y ? d1 : d0;
    int* cursor = blockIdx.y ? c1 : c0;
    int* ssrc = blockIdx.y ? o1 : o0;
    if (e < E) {
        int p = atomicAdd(&cursor[dst[e]], 1);
        ssrc[p] = src[e];
    }
}

// ---------------- mean-pool + relu (both graphs, fp16 input) ----------------
__global__ __launch_bounds__(256) void pool_k(const u16* __restrict__ H0, const u16* __restrict__ H1,
                                              const int* __restrict__ batch,
                                              float* __restrict__ p0, float* __restrict__ p1, int M) {
    const u16* Hf = blockIdx.y ? H1 : H0;
    float* pooled = blockIdx.y ? p1 : p0;
    __shared__ int lo_s, hi_s;
    __shared__ float smx[256], smy[256];
    int g = blockIdx.x;
    if (threadIdx.x == 0) {
        int lo = 0, hi = M;
        while (lo < hi) { int mid = (lo + hi) >> 1; if (batch[mid] < g) lo = mid + 1; else hi = mid; }
        lo_s = lo;
        int lo2 = lo, hi2 = M;
        while (lo2 < hi2) { int mid = (lo2 + hi2) >> 1; if (batch[mid] < g + 1) lo2 = mid + 1; else hi2 = mid; }
        hi_s = lo2;
    }
    __syncthreads();
    int lo = lo_s, hi = hi_s;
    int c2 = threadIdx.x & 63, quarter = threadIdx.x >> 6;
    float ax = 0.f, ay = 0.f;
    for (int i = lo + quarter; i < hi; i += 4) {
        float2 v = up2(*reinterpret_cast<const unsigned*>(Hf + (size_t)i * HDIM + c2 * 2));
        ax += v.x; ay += v.y;
    }
    smx[threadIdx.x] = ax; smy[threadIdx.x] = ay;
    __syncthreads();
    if (quarter == 0) {
        float sx = smx[c2] + smx[c2 + 64] + smx[c2 + 128] + smx[c2 + 192];
        float sy = smy[c2] + smy[c2 + 64] + smy[c2 + 128] + smy[c2 + 192];
        float cnt = (float)(hi - lo); if (cnt < 1.f) cnt = 1.f;
        pooled[g * HDIM + c2 * 2]     = fmaxf(sx / cnt, 0.f);
        pooled[g * HDIM + c2 * 2 + 1] = fmaxf(sy / cnt, 0.f);
    }
}

// ---------------- prediction head -------------------------------------------
__global__ void pred_kernel(const float* __restrict__ pa, const float* __restrict__ pv,
                            const float* __restrict__ pW, const float* __restrict__ pb,
                            float* __restrict__ out) {
    int g = blockIdx.x, lane = threadIdx.x; // 64 threads
    float s = pa[g * HDIM + lane] * pW[lane]
            + pa[g * HDIM + 64 + lane] * pW[64 + lane]
            + pv[g * HDIM + lane] * pW[HDIM + lane]
            + pv[g * HDIM + 64 + lane] * pW[192 + lane];
    for (int off = 32; off; off >>= 1) s += __shfl_down(s, off);
    if (lane == 0) out[g] = s + pb[0];
}

extern "C" void kernel_launch(void* const* d_in, const int* in_sizes, int n_in,
                              void* d_out, int out_size, void* d_ws, size_t ws_size,
                              hipStream_t stream) {
    const float* atom_x   = (const float*)d_in[0];
    const float* voro_x   = (const float*)d_in[1];
    const int*   atom_ei  = (const int*)d_in[2];
    const int*   voro_ei  = (const int*)d_in[3];
    const int*   batch    = (const int*)d_in[4];
    const float* W_at_in  = (const float*)d_in[5];
    const float* W_vo_in  = (const float*)d_in[6];
    const float* atom_W   = (const float*)d_in[7];
    const float* voro_W   = (const float*)d_in[8];
    const float* atom_Wih = (const float*)d_in[9];
    const float* atom_Whh = (const float*)d_in[10];
    const float* atom_bih = (const float*)d_in[11];
    const float* atom_bhh = (const float*)d_in[12];
    const float* voro_Wih = (const float*)d_in[13];
    const float* voro_Whh = (const float*)d_in[14];
    const float* voro_bih = (const float*)d_in[15];
    const float* voro_bhh = (const float*)d_in[16];
    const float* pred_W   = (const float*)d_in[17];
    const float* pred_b   = (const float*)d_in[18];
    float* out = (float*)d_out;

    const int Nn = in_sizes[4];
    const int Ee = in_sizes[2] / 2;
    const int Gg = out_size;
    const int Npad = (Nn + 31) & ~31;
    const int nbScan = (Nn + 1023) / 1024;

    char* base = (char*)d_ws;
    size_t off = 0;
    auto alloc = [&](size_t bytes) -> char* {
        char* p = base + off;
        off = (off + bytes + 255) & ~(size_t)255;
        return p;
    };

    u16 *HhA[2], *HhB[2];
    u16 *WfHi[2], *WfLo[2], *WhHi[2], *WhLo[2], *WnHi[2], *WnLo[2];
    int *row_off[2], *cursor[2], *ssrc[2], *bt[2];
    for (int t = 0; t < 2; ++t) {
        HhA[t] = (u16*)alloc((size_t)Npad * HDIM * 2);
        HhB[t] = (u16*)alloc((size_t)Npad * HDIM * 2);
        WfHi[t] = (u16*)alloc(4 * 49152 * 2); WfLo[t] = (u16*)alloc(4 * 49152 * 2);
        WhHi[t] = (u16*)alloc(384 * 128 * 2); WhLo[t] = (u16*)alloc(384 * 128 * 2);
        WnHi[t] = (u16*)alloc(128 * 64 * 2);  WnLo[t] = (u16*)alloc(128 * 64 * 2);
        row_off[t] = (int*)alloc((size_t)(Nn + 1) * 4);
        cursor[t]  = (int*)alloc((size_t)Nn * 4);
        ssrc[t]    = (int*)alloc((size_t)Ee * 4);
        bt[t]      = (int*)alloc((size_t)(nbScan + 1) * 4);
    }
    float* pooledA = (float*)alloc((size_t)Gg * HDIM * 4);
    float* pooledV = (float*)alloc((size_t)Gg * HDIM * 4);

    const float* Wst[2] = {atom_W, voro_W};
    const float* Wih[2] = {atom_Wih, voro_Wih};
    const float* Whh[2] = {atom_Whh, voro_Whh};
    const float* Win[2] = {W_at_in, W_vo_in};

    for (int t = 0; t < 2; ++t) {
        prep_wfull<<<dim3(192, 4), 256, 0, stream>>>(Wst[t], Wih[t], WfHi[t], WfLo[t]);
        prep_split<<<192, 256, 0, stream>>>(Whh[t], WhHi[t], WhLo[t], 384 * 128);
        prep_win<<<32, 256, 0, stream>>>(Win[t], WnHi[t], WnLo[t]);
    }

    const int eb  = (Ee + 255) / 256;
    const int nb  = (Nn + 255) / 256;
    const int gbs = Npad / 32;

    embed_k<<<dim3(gbs, 2), 256, 0, stream>>>(atom_x, voro_x,
                                              WnHi[0], WnLo[0], WnHi[1], WnLo[1],
                                              HhA[0], HhA[1], Nn);

    zero_int2<<<dim3(nb, 2), 256, 0, stream>>>(cursor[0], cursor[1], Nn);
    hist_k2<<<dim3(eb, 2), 256, 0, stream>>>(atom_ei + Ee, voro_ei + Ee, cursor[0], cursor[1], Ee);
    scan_part<<<dim3(nbScan, 2), 256, 0, stream>>>(cursor[0], cursor[1], row_off[0], row_off[1],
                                                   bt[0], bt[1], Nn);
    scan_tops<<<2, 64, 0, stream>>>(bt[0], bt[1], nbScan);
    scan_fix<<<dim3((Nn + 1 + 255) / 256, 2), 256, 0, stream>>>(row_off[0], row_off[1], bt[0], bt[1],
                                                                cursor[0], cursor[1], Nn, nbScan);
    scatter_k2<<<dim3(eb, 2), 256, 0, stream>>>(atom_ei, atom_ei + Ee, voro_ei, voro_ei + Ee,
                                                cursor[0], cursor[1], ssrc[0], ssrc[1], Ee);

    u16 *gA0 = HhA[0], *gB0 = HhB[0], *gA1 = HhA[1], *gB1 = HhB[1];
    for (int s = 0; s < 4; ++s) {
        step_k<<<dim3(gbs, 2), 512, 0, stream>>>(
            gA0, gA1, row_off[0], row_off[1], ssrc[0], ssrc[1],
            WfHi[0] + (size_t)s * 49152, WfLo[0] + (size_t)s * 49152,
            WfHi[1] + (size_t)s * 49152, WfLo[1] + (size_t)s * 49152,
            WhHi[0], WhLo[0], WhHi[1], WhLo[1],
            atom_bih, atom_bhh, voro_bih, voro_bhh,
            gB0, gB1, Nn);
        u16* up;
        up = gA0; gA0 = gB0; gB0 = up;
        up = gA1; gA1 = gB1; gB1 = up;
    }
    pool_k<<<dim3(Gg, 2), 256, 0, stream>>>(gA0, gA1, batch, pooledA, pooledV, Nn);
    pred_kernel<<<Gg, 64, 0, stream>>>(pooledA, pooledV, pred_W, pred_b, out);
}

// Round 13
// 1140.560 us; speedup vs baseline: 1.4050x; 1.4050x over previous
//
#include <hip/hip_runtime.h>
#include <hip/hip_fp16.h>
#include <math.h>

#define HDIM 128
typedef unsigned short u16;
typedef __attribute__((ext_vector_type(8))) short bf16x8;
typedef __attribute__((ext_vector_type(4))) float f32x4;

__device__ __forceinline__ u16 f2bf(float x) {
    unsigned u = __float_as_uint(x);
    u = (u + 0x7FFFu + ((u >> 16) & 1u)) >> 16;
    return (u16)u;
}
__device__ __forceinline__ float bf2f(u16 h) {
    return __uint_as_float(((unsigned)h) << 16);
}
__device__ __forceinline__ bf16x8 ld8(const u16* p) {
    return *reinterpret_cast<const bf16x8*>(p);
}
__device__ __forceinline__ void split8(const float* v, bf16x8& hi, bf16x8& lo) {
#pragma unroll
    for (int j = 0; j < 8; ++j) {
        unsigned u = __float_as_uint(v[j]);
        unsigned h = (u + 0x7FFFu + ((u >> 16) & 1u)) >> 16;
        float rem = v[j] - __uint_as_float(h << 16);
        hi[j] = (short)h;
        lo[j] = (short)(__float_as_uint(rem) >> 16);
    }
}
__device__ __forceinline__ float2 up2(unsigned u) {
    __half2 h = *reinterpret_cast<__half2*>(&u);
    float2 f; f.x = __low2float(h); f.y = __high2float(h); return f;
}
__device__ __forceinline__ u16 f2h(float x) {
    __half t = __float2half(x);
    return *reinterpret_cast<u16*>(&t);
}
__device__ __forceinline__ void acc_u4(float* a, uint4 u, float w) {
    float2 v0 = up2(u.x), v1 = up2(u.y), v2 = up2(u.z), v3 = up2(u.w);
    a[0] = fmaf(w, v0.x, a[0]); a[1] = fmaf(w, v0.y, a[1]);
    a[2] = fmaf(w, v1.x, a[2]); a[3] = fmaf(w, v1.y, a[3]);
    a[4] = fmaf(w, v2.x, a[4]); a[5] = fmaf(w, v2.y, a[5]);
    a[6] = fmaf(w, v3.x, a[6]); a[7] = fmaf(w, v3.y, a[7]);
}
#define MFMA(acc, a, b) acc = __builtin_amdgcn_mfma_f32_16x16x32_bf16(a, b, acc, 0, 0, 0)

// ---------------- weight prep -----------------------------------------------
// Wfull[s][c][k] = dot(Ws[s][k][:], Wih[c][:])  (gi = (hagg@Ws)@Wih^T), hi/lo
__global__ __launch_bounds__(256) void prep_wfull(const float* __restrict__ Ws,
                                                  const float* __restrict__ Wih,
                                                  u16* __restrict__ hi, u16* __restrict__ lo) {
    int s = blockIdx.y;
    int idx = blockIdx.x * 256 + threadIdx.x;   // [0, 49152)
    int c2 = idx >> 7, r = idx & 127;
    const float* wr = Ws + (size_t)s * 16384 + (size_t)r * 128;
    const float* wc = Wih + (size_t)c2 * 128;
    float acc = 0.f;
#pragma unroll 8
    for (int k = 0; k < 128; k += 4) {
        float4 a = *reinterpret_cast<const float4*>(wr + k);
        float4 b = *reinterpret_cast<const float4*>(wc + k);
        acc += a.x * b.x + a.y * b.y + a.z * b.z + a.w * b.w;
    }
    size_t o = (size_t)s * 49152 + idx;
    u16 h = f2bf(acc);
    hi[o] = h; lo[o] = f2bf(acc - bf2f(h));
}

__global__ __launch_bounds__(256) void prep_split(const float* __restrict__ W,
                                                  u16* __restrict__ hi, u16* __restrict__ lo, int n) {
    int i = blockIdx.x * 256 + threadIdx.x;
    if (i < n) { float v = W[i]; u16 h = f2bf(v); hi[i] = h; lo[i] = f2bf(v - bf2f(h)); }
}

// WinT[r][c] = W_in[c][r], [128][64]
__global__ __launch_bounds__(256) void prep_win(const float* __restrict__ W,
                                                u16* __restrict__ hi, u16* __restrict__ lo) {
    int idx = blockIdx.x * 256 + threadIdx.x;        // 0..8191
    int r = idx >> 6, c = idx & 63;
    float v = W[(size_t)c * 128 + r];
    u16 h = f2bf(v);
    hi[idx] = h; lo[idx] = f2bf(v - bf2f(h));
}

// ---------------- embed: Hh = fp16(tanh(X @ Win)), fp32 X read directly -----
__global__ __launch_bounds__(256) void embed_k(const float* __restrict__ X0, const float* __restrict__ X1,
                                               const u16* __restrict__ Bhi0, const u16* __restrict__ Blo0,
                                               const u16* __restrict__ Bhi1, const u16* __restrict__ Blo1,
                                               u16* __restrict__ Hh0, u16* __restrict__ Hh1, int Nn) {
    const int by = blockIdx.y;
    const float* X = by ? X1 : X0;
    const u16* Bhi = by ? Bhi1 : Bhi0;  const u16* Blo = by ? Blo1 : Blo0;
    u16* Hh = by ? Hh1 : Hh0;
    const int tid = threadIdx.x, wave = tid >> 6, lane = tid & 63;
    const int row0 = blockIdx.x * 32, cs = wave * 32;
    const int lr = lane & 15, lk = (lane >> 4) * 8;
    f32x4 acc[2][2];
#pragma unroll
    for (int i = 0; i < 2; ++i)
#pragma unroll
        for (int j = 0; j < 2; ++j) acc[i][j] = (f32x4)0.f;
#pragma unroll
    for (int kc = 0; kc < 2; ++kc) {
        float xv[8];
        bf16x8 ah0, al0, ah1, al1;
        const int r0i = row0 + lr;
        if (r0i < Nn) {
            const float* xp = X + (size_t)r0i * 64 + kc * 32 + lk;
            *reinterpret_cast<float4*>(&xv[0]) = *reinterpret_cast<const float4*>(xp);
            *reinterpret_cast<float4*>(&xv[4]) = *reinterpret_cast<const float4*>(xp + 4);
        } else {
#pragma unroll
            for (int j = 0; j < 8; ++j) xv[j] = 0.f;
        }
        split8(xv, ah0, al0);
        const int r1i = row0 + 16 + lr;
        if (r1i < Nn) {
            const float* xp = X + (size_t)r1i * 64 + kc * 32 + lk;
            *reinterpret_cast<float4*>(&xv[0]) = *reinterpret_cast<const float4*>(xp);
            *reinterpret_cast<float4*>(&xv[4]) = *reinterpret_cast<const float4*>(xp + 4);
        } else {
#pragma unroll
            for (int j = 0; j < 8; ++j) xv[j] = 0.f;
        }
        split8(xv, ah1, al1);
#pragma unroll
        for (int cf = 0; cf < 2; ++cf) {
            const size_t bo = (size_t)(cs + cf * 16 + lr) * 64 + kc * 32 + lk;
            bf16x8 bh = ld8(Bhi + bo), bl = ld8(Blo + bo);
            MFMA(acc[0][cf], ah0, bh); MFMA(acc[0][cf], ah0, bl); MFMA(acc[0][cf], al0, bh);
            MFMA(acc[1][cf], ah1, bh); MFMA(acc[1][cf], ah1, bl); MFMA(acc[1][cf], al1, bh);
        }
    }
#pragma unroll
    for (int rf = 0; rf < 2; ++rf)
#pragma unroll
        for (int cf = 0; cf < 2; ++cf)
#pragma unroll
            for (int rg = 0; rg < 4; ++rg) {
                int row = row0 + rf * 16 + (lane >> 4) * 4 + rg;
                int col = cs + cf * 16 + lr;
                Hh[(size_t)row * HDIM + col] = f2h(tanhf(acc[rf][cf][rg]));
            }
}

// ---------------- fused step: 4-edges-per-load gather, GRU GEMM; 2 graphs ---
// 512 threads = 8 waves; block covers 32 node-rows of graph blockIdx.y.
// phase 1: wave w gathers nodes w*4..w*4+3; each 16-lane group loads one
//          256B row as uint4 (4 edges per wave-instruction, 1KB).
// phase 2: wave w computes cols w*16..w*16+16 of all 6 gate strips via MFMA.
__global__ __launch_bounds__(512, 4) void step_k(const u16* __restrict__ Hh0, const u16* __restrict__ Hh1,
                                                 const int* __restrict__ ro0, const int* __restrict__ ro1,
                                                 const int* __restrict__ ss0, const int* __restrict__ ss1,
                                                 const u16* __restrict__ Wf0h, const u16* __restrict__ Wf0l,
                                                 const u16* __restrict__ Wf1h, const u16* __restrict__ Wf1l,
                                                 const u16* __restrict__ Wh0h, const u16* __restrict__ Wh0l,
                                                 const u16* __restrict__ Wh1h, const u16* __restrict__ Wh1l,
                                                 const float* __restrict__ bi0, const float* __restrict__ bh0,
                                                 const float* __restrict__ bi1, const float* __restrict__ bh1,
                                                 u16* __restrict__ Hn0, u16* __restrict__ Hn1, int Nn) {
    __shared__ u16 agh[32][136];
    __shared__ u16 agl[32][136];
    __shared__ u16 hhh[32][136];
    __shared__ u16 hhl[32][136];
    __shared__ int eidx[1024];
    const int by = blockIdx.y;
    const u16* Hh = by ? Hh1 : Hh0;
    const int* row_off = by ? ro1 : ro0;
    const int* ssrc = by ? ss1 : ss0;
    const int tid = threadIdx.x, wave = tid >> 6, lane = tid & 63;
    const int row0 = blockIdx.x * 32;
    const int g16 = lane >> 4, l16 = lane & 15;

    // ---- phase 0: stage edge indices into LDS ----
    const int rowEnd = (row0 + 32 < Nn) ? row0 + 32 : Nn;
    const int eLo = row_off[row0];
    const int nE = row_off[rowEnd] - eLo;
    for (int i = tid; i < nE && i < 1024; i += 512) eidx[i] = ssrc[eLo + i];
    __syncthreads();

    // ---- phase 1: gather neighbor-sum, 4 edges per load instruction ----
#pragma unroll
    for (int q = 0; q < 4; ++q) {
        const int nl = wave * 4 + q;
        const int node = row0 + nl;
        float a8[8];
#pragma unroll
        for (int j = 0; j < 8; ++j) a8[j] = 0.f;
        if (node < Nn) {
            const int lo = row_off[node] - eLo;
            const int hi = row_off[node + 1] - eLo;
            if (hi > lo) {
                // masked 16-edge burst (one latency window for ~89% of nodes)
                uint4 u[4]; float w[4];
#pragma unroll
                for (int b = 0; b < 4; ++b) {
                    const int p = lo + b * 4 + g16;
                    const bool val = p < hi;
                    const int ps = val ? p : lo;
                    const int idx = (ps < 1024) ? eidx[ps] : ssrc[eLo + ps];
                    u[b] = *reinterpret_cast<const uint4*>(Hh + (size_t)idx * HDIM + l16 * 8);
                    w[b] = val ? 1.f : 0.f;
                }
#pragma unroll
                for (int b = 0; b < 4; ++b) acc_u4(a8, u[b], w[b]);
                // overflow (deg > 16), 4 edges per iteration
                for (int i = lo + 16; i < hi; i += 4) {
                    const int p = i + g16;
                    const bool val = p < hi;
                    const int ps = val ? p : lo;
                    const int idx = (ps < 1024) ? eidx[ps] : ssrc[eLo + ps];
                    uint4 uu = *reinterpret_cast<const uint4*>(Hh + (size_t)idx * HDIM + l16 * 8);
                    acc_u4(a8, uu, val ? 1.f : 0.f);
                }
            }
        }
        // cross-group reduce: each lane ends with full sums for its 8 cols
#pragma unroll
        for (int j = 0; j < 8; ++j) {
            a8[j] += __shfl_xor(a8[j], 16);
            a8[j] += __shfl_xor(a8[j], 32);
        }
        if (g16 == 0) {
            bf16x8 h8, l8;
            split8(a8, h8, l8);
            *reinterpret_cast<bf16x8*>(&agh[nl][l16 * 8]) = h8;
            *reinterpret_cast<bf16x8*>(&agl[nl][l16 * 8]) = l8;
        }
    }

    // ---- phase 1c: stage own h rows (fp16 exact), split -> bf16 hi/lo LDS ----
    {
        const int r = tid >> 4, c0 = (tid & 15) * 8;
        float v[8];
        const int row = row0 + r;
        if (row < Nn) {
            const u16* hp = Hh + (size_t)row * HDIM + c0;
#pragma unroll
            for (int j = 0; j < 4; ++j) {
                float2 f = up2(*reinterpret_cast<const unsigned*>(hp + j * 2));
                v[j * 2] = f.x; v[j * 2 + 1] = f.y;
            }
        } else {
#pragma unroll
            for (int j = 0; j < 8; ++j) v[j] = 0.f;
        }
        bf16x8 hi, lo;
        split8(v, hi, lo);
        *reinterpret_cast<bf16x8*>(&hhh[r][c0]) = hi;
        *reinterpret_cast<bf16x8*>(&hhl[r][c0]) = lo;
    }
    __syncthreads();

    // ---- phase 2: GEMM + gates; wave owns 16 cols (cs), 32 rows ----
    const u16* Wfhi = by ? Wf1h : Wf0h;  const u16* Wflo = by ? Wf1l : Wf0l;
    const u16* Whhi = by ? Wh1h : Wh0h;  const u16* Whlo = by ? Wh1l : Wh0l;
    const float* bih = by ? bi1 : bi0;   const float* bhh = by ? bh1 : bh0;
    u16* Hnh = by ? Hn1 : Hn0;
    const int lr = lane & 15, lk = (lane >> 4) * 8, cs = wave * 16;
    f32x4 accI[2][3], accH[2][3];
#pragma unroll
    for (int rf = 0; rf < 2; ++rf)
#pragma unroll
        for (int g = 0; g < 3; ++g) { accI[rf][g] = (f32x4)0.f; accH[rf][g] = (f32x4)0.f; }
#pragma unroll
    for (int kc = 0; kc < 4; ++kc) {
        bf16x8 ga[2], gl[2], ha[2], hl[2];
#pragma unroll
        for (int rf = 0; rf < 2; ++rf) {
            const int rr = rf * 16 + lr, cc = kc * 32 + lk;
            ga[rf] = *reinterpret_cast<const bf16x8*>(&agh[rr][cc]);
            gl[rf] = *reinterpret_cast<const bf16x8*>(&agl[rr][cc]);
            ha[rf] = *reinterpret_cast<const bf16x8*>(&hhh[rr][cc]);
            hl[rf] = *reinterpret_cast<const bf16x8*>(&hhl[rr][cc]);
        }
#pragma unroll
        for (int g = 0; g < 3; ++g) {
            const size_t bo = (size_t)(g * 128 + cs + lr) * HDIM + kc * 32 + lk;
            bf16x8 fh = ld8(Wfhi + bo), fl = ld8(Wflo + bo);
            bf16x8 wh = ld8(Whhi + bo), wl = ld8(Whlo + bo);
#pragma unroll
            for (int rf = 0; rf < 2; ++rf) {
                MFMA(accI[rf][g], ga[rf], fh); MFMA(accI[rf][g], ga[rf], fl); MFMA(accI[rf][g], gl[rf], fh);
                MFMA(accH[rf][g], ha[rf], wh); MFMA(accH[rf][g], ha[rf], wl); MFMA(accH[rf][g], hl[rf], wh);
            }
        }
    }
    const int c = cs + lr;
    const float bir = bih[c], biz = bih[128 + c], bin = bih[256 + c];
    const float bhr = bhh[c], bhz = bhh[128 + c], bhn = bhh[256 + c];
#pragma unroll
    for (int rf = 0; rf < 2; ++rf)
#pragma unroll
        for (int rg = 0; rg < 4; ++rg) {
            const int rl = rf * 16 + (lane >> 4) * 4 + rg;
            const int row = row0 + rl;
            float gir = accI[rf][0][rg] + bir;
            float giz = accI[rf][1][rg] + biz;
            float gin = accI[rf][2][rg] + bin;
            float ghr = accH[rf][0][rg] + bhr;
            float ghz = accH[rf][1][rg] + bhz;
            float ghn = accH[rf][2][rg] + bhn;
            float r = 1.f / (1.f + expf(-(gir + ghr)));
            float z = 1.f / (1.f + expf(-(giz + ghz)));
            float nn = tanhf(gin + r * ghn);
            float hold = bf2f(hhh[rl][c]) + bf2f(hhl[rl][c]);
            float hn = (1.f - z) * nn + z * hold;
            if (row < Nn) Hnh[(size_t)row * HDIM + c] = f2h(hn);
        }
}

// ---------------- CSR build (both graphs via blockIdx.y) --------------------
__global__ void zero_int2(int* p0, int* p1, int n) {
    int i = blockIdx.x * 256 + threadIdx.x;
    int* p = blockIdx.y ? p1 : p0;
    if (i < n) p[i] = 0;
}

__global__ void hist_k2(const int* __restrict__ d0, const int* __restrict__ d1,
                        int* __restrict__ c0, int* __restrict__ c1, int E) {
    int e = blockIdx.x * 256 + threadIdx.x;
    const int* dst = blockIdx.y ? d1 : d0;
    int* cnt = blockIdx.y ? c1 : c0;
    if (e < E) atomicAdd(&cnt[dst[e]], 1);
}

// parallel scan, 3 phases. A: per-block (1024 elems) partial scan + block total.
__global__ __launch_bounds__(256) void scan_part(const int* __restrict__ c0, const int* __restrict__ c1,
                                                 int* __restrict__ r0, int* __restrict__ r1,
                                                 int* __restrict__ bt0, int* __restrict__ bt1, int n) {
    const int* cnt = blockIdx.y ? c1 : c0;
    int* ro = blockIdx.y ? r1 : r0;
    int* bt = blockIdx.y ? bt1 : bt0;
    __shared__ int wsum[4];
    const int tid = threadIdx.x, lane = tid & 63, wv = tid >> 6;
    const int i0 = blockIdx.x * 1024 + tid * 4;
    int v[4];
#pragma unroll
    for (int j = 0; j < 4; ++j) v[j] = (i0 + j < n) ? cnt[i0 + j] : 0;
    int s = v[0] + v[1] + v[2] + v[3];
    int x = s;
#pragma unroll
    for (int off = 1; off < 64; off <<= 1) { int t = __shfl_up(x, off); if (lane >= off) x += t; }
    if (lane == 63) wsum[wv] = x;
    __syncthreads();
    int wbase = 0;
#pragma unroll
    for (int w = 0; w < 4; ++w) wbase += (w < wv) ? wsum[w] : 0;
    int run = wbase + x - s;
#pragma unroll
    for (int j = 0; j < 4; ++j) { if (i0 + j < n) ro[i0 + j] = run; run += v[j]; }
    if (tid == 255) bt[blockIdx.x] = wbase + x;
}

// B: exclusive-scan the block totals (nb <= 64); bt[nb] = grand total.
__global__ void scan_tops(int* __restrict__ bt0, int* __restrict__ bt1, int nb) {
    int* bt = blockIdx.x ? bt1 : bt0;
    const int lane = threadIdx.x;   // 64 threads
    int v = (lane < nb) ? bt[lane] : 0;
    int x = v;
#pragma unroll
    for (int off = 1; off < 64; off <<= 1) { int t = __shfl_up(x, off); if (lane >= off) x += t; }
    if (lane < nb) bt[lane] = x - v;
    if (lane == 63) bt[nb] = x;
}

// C: add block offsets; write cursor copy and row_off[n].
__global__ void scan_fix(int* __restrict__ r0, int* __restrict__ r1,
                         const int* __restrict__ bt0, const int* __restrict__ bt1,
                         int* __restrict__ cur0, int* __restrict__ cur1, int n, int nb) {
    const int i = blockIdx.x * 256 + threadIdx.x;
    int* ro = blockIdx.y ? r1 : r0;
    const int* bt = blockIdx.y ? bt1 : bt0;
    int* cur = blockIdx.y ? cur1 : cur0;
    if (i < n) {
        int val = ro[i] + bt[i >> 10];
        ro[i] = val;
        cur[i] = val;
    } else if (i == n) {
        ro[n] = bt[nb];
    }
}

__global__ void scatter_k2(const int* __restrict__ s0, const int* __restrict__ d0,
                           const int* __restrict__ s1, const int* __restrict__ d1,
                           int* __restrict__ c0, int* __restrict__ c1,
                           int* __restrict__ o0, int* __restrict__ o1, int E) {
    int e = blockIdx.x * 256 + threadIdx.x;
    const int* src = blockIdx.y ? s1 : s0;
    const int* dst = blockIdx.y ? d1 : d0;
    int* cursor = blockIdx.y ? c1 : c0;
    int* ssrc = blockIdx.y ? o1 : o0;
    if (e < E) {
        int p = atomicAdd(&cursor[dst[e]], 1);
        ssrc[p] = src[e];
    }
}

// ---------------- mean-pool + relu (both graphs, fp16 input) ----------------
__global__ __launch_bounds__(256) void pool_k(const u16* __restrict__ H0, const u16* __restrict__ H1,
                                              const int* __restrict__ batch,
                                              float* __restrict__ p0, float* __restrict__ p1, int M) {
    const u16* Hf = blockIdx.y ? H1 : H0;
    float* pooled = blockIdx.y ? p1 : p0;
    __shared__ int lo_s, hi_s;
    __shared__ float smx[256], smy[256];
    int g = blockIdx.x;
    if (threadIdx.x == 0) {
        int lo = 0, hi = M;
        while (lo < hi) { int mid = (lo + hi) >> 1; if (batch[mid] < g) lo = mid + 1; else hi = mid; }
        lo_s = lo;
        int lo2 = lo, hi2 = M;
        while (lo2 < hi2) { int mid = (lo2 + hi2) >> 1; if (batch[mid] < g + 1) lo2 = mid + 1; else hi2 = mid; }
        hi_s = lo2;
    }
    __syncthreads();
    int lo = lo_s, hi = hi_s;
    int c2 = threadIdx.x & 63, quarter = threadIdx.x >> 6;
    float ax = 0.f, ay = 0.f;
    for (int i = lo + quarter; i < hi; i += 4) {
        float2 v = up2(*reinterpret_cast<const unsigned*>(Hf + (size_t)i * HDIM + c2 * 2));
        ax += v.x; ay += v.y;
    }
    smx[threadIdx.x] = ax; smy[threadIdx.x] = ay;
    __syncthreads();
    if (quarter == 0) {
        float sx = smx[c2] + smx[c2 + 64] + smx[c2 + 128] + smx[c2 + 192];
        float sy = smy[c2] + smy[c2 + 64] + smy[c2 + 128] + smy[c2 + 192];
        float cnt = (float)(hi - lo); if (cnt < 1.f) cnt = 1.f;
        pooled[g * HDIM + c2 * 2]     = fmaxf(sx / cnt, 0.f);
        pooled[g * HDIM + c2 * 2 + 1] = fmaxf(sy / cnt, 0.f);
    }
}

// ---------------- prediction head -------------------------------------------
__global__ void pred_kernel(const float* __restrict__ pa, const float* __restrict__ pv,
                            const float* __restrict__ pW, const float* __restrict__ pb,
                            float* __restrict__ out) {
    int g = blockIdx.x, lane = threadIdx.x; // 64 threads
    float s = pa[g * HDIM + lane] * pW[lane]
            + pa[g * HDIM + 64 + lane] * pW[64 + lane]
            + pv[g * HDIM + lane] * pW[HDIM + lane]
            + pv[g * HDIM + 64 + lane] * pW[192 + lane];
    for (int off = 32; off; off >>= 1) s += __shfl_down(s, off);
    if (lane == 0) out[g] = s + pb[0];
}

extern "C" void kernel_launch(void* const* d_in, const int* in_sizes, int n_in,
                              void* d_out, int out_size, void* d_ws, size_t ws_size,
                              hipStream_t stream) {
    const float* atom_x   = (const float*)d_in[0];
    const float* voro_x   = (const float*)d_in[1];
    const int*   atom_ei  = (const int*)d_in[2];
    const int*   voro_ei  = (const int*)d_in[3];
    const int*   batch    = (const int*)d_in[4];
    const float* W_at_in  = (const float*)d_in[5];
    const float* W_vo_in  = (const float*)d_in[6];
    const float* atom_W   = (const float*)d_in[7];
    const float* voro_W   = (const float*)d_in[8];
    const float* atom_Wih = (const float*)d_in[9];
    const float* atom_Whh = (const float*)d_in[10];
    const float* atom_bih = (const float*)d_in[11];
    const float* atom_bhh = (const float*)d_in[12];
    const float* voro_Wih = (const float*)d_in[13];
    const float* voro_Whh = (const float*)d_in[14];
    const float* voro_bih = (const float*)d_in[15];
    const float* voro_bhh = (const float*)d_in[16];
    const float* pred_W   = (const float*)d_in[17];
    const float* pred_b   = (const float*)d_in[18];
    float* out = (float*)d_out;

    const int Nn = in_sizes[4];
    const int Ee = in_sizes[2] / 2;
    const int Gg = out_size;
    const int Npad = (Nn + 31) & ~31;
    const int nbScan = (Nn + 1023) / 1024;

    char* base = (char*)d_ws;
    size_t off = 0;
    auto alloc = [&](size_t bytes) -> char* {
        char* p = base + off;
        off = (off + bytes + 255) & ~(size_t)255;
        return p;
    };

    u16 *HhA[2], *HhB[2];
    u16 *WfHi[2], *WfLo[2], *WhHi[2], *WhLo[2], *WnHi[2], *WnLo[2];
    int *row_off[2], *cursor[2], *ssrc[2], *bt[2];
    for (int t = 0; t < 2; ++t) {
        HhA[t] = (u16*)alloc((size_t)Npad * HDIM * 2);
        HhB[t] = (u16*)alloc((size_t)Npad * HDIM * 2);
        WfHi[t] = (u16*)alloc(4 * 49152 * 2); WfLo[t] = (u16*)alloc(4 * 49152 * 2);
        WhHi[t] = (u16*)alloc(384 * 128 * 2); WhLo[t] = (u16*)alloc(384 * 128 * 2);
        WnHi[t] = (u16*)alloc(128 * 64 * 2);  WnLo[t] = (u16*)alloc(128 * 64 * 2);
        row_off[t] = (int*)alloc((size_t)(Nn + 1) * 4);
        cursor[t]  = (int*)alloc((size_t)Nn * 4);
        ssrc[t]    = (int*)alloc((size_t)Ee * 4);
        bt[t]      = (int*)alloc((size_t)(nbScan + 1) * 4);
    }
    float* pooledA = (float*)alloc((size_t)Gg * HDIM * 4);
    float* pooledV = (float*)alloc((size_t)Gg * HDIM * 4);

    const float* Wst[2] = {atom_W, voro_W};
    const float* Wih[2] = {atom_Wih, voro_Wih};
    const float* Whh[2] = {atom_Whh, voro_Whh};
    const float* Win[2] = {W_at_in, W_vo_in};

    for (int t = 0; t < 2; ++t) {
        prep_wfull<<<dim3(192, 4), 256, 0, stream>>>(Wst[t], Wih[t], WfHi[t], WfLo[t]);
        prep_split<<<192, 256, 0, stream>>>(Whh[t], WhHi[t], WhLo[t], 384 * 128);
        prep_win<<<32, 256, 0, stream>>>(Win[t], WnHi[t], WnLo[t]);
    }

    const int eb  = (Ee + 255) / 256;
    const int nb  = (Nn + 255) / 256;
    const int gbs = Npad / 32;

    embed_k<<<dim3(gbs, 2), 256, 0, stream>>>(atom_x, voro_x,
                                              WnHi[0], WnLo[0], WnHi[1], WnLo[1],
                                              HhA[0], HhA[1], Nn);

    zero_int2<<<dim3(nb, 2), 256, 0, stream>>>(cursor[0], cursor[1], Nn);
    hist_k2<<<dim3(eb, 2), 256, 0, stream>>>(atom_ei + Ee, voro_ei + Ee, cursor[0], cursor[1], Ee);
    scan_part<<<dim3(nbScan, 2), 256, 0, stream>>>(cursor[0], cursor[1], row_off[0], row_off[1],
                                                   bt[0], bt[1], Nn);
    scan_tops<<<2, 64, 0, stream>>>(bt[0], bt[1], nbScan);
    scan_fix<<<dim3((Nn + 1 + 255) / 256, 2), 256, 0, stream>>>(row_off[0], row_off[1], bt[0], bt[1],
                                                                cursor[0], cursor[1], Nn, nbScan);
    scatter_k2<<<dim3(eb, 2), 256, 0, stream>>>(atom_ei, atom_ei + Ee, voro_ei, voro_ei + Ee,
                                                cursor[0], cursor[1], ssrc[0], ssrc[1], Ee);

    u16 *gA0 = HhA[0], *gB0 = HhB[0], *gA1 = HhA[1], *gB1 = HhB[1];
    for (int s = 0; s < 4; ++s) {
        step_k<<<dim3(gbs, 2), 512, 0, stream>>>(
            gA0, gA1, row_off[0], row_off[1], ssrc[0], ssrc[1],
            WfHi[0] + (size_t)s * 49152, WfLo[0] + (size_t)s * 49152,
            WfHi[1] + (size_t)s * 49152, WfLo[1] + (size_t)s * 49152,
            WhHi[0], WhLo[0], WhHi[1], WhLo[1],
            atom_bih, atom_bhh, voro_bih, voro_bhh,
            gB0, gB1, Nn);
        u16* up;
        up = gA0; gA0 = gB0; gB0 = up;
        up = gA1; gA1 = gB1; gB1 = up;
    }
    pool_k<<<dim3(Gg, 2), 256, 0, stream>>>(gA0, gA1, batch, pooledA, pooledV, Nn);
    pred_kernel<<<Gg, 64, 0, stream>>>(pooledA, pooledV, pred_W, pred_b, out);
}

// Round 14
// 1098.644 us; speedup vs baseline: 1.4586x; 1.0382x over previous
//
#include <hip/hip_runtime.h>
#include <hip/hip_fp16.h>
#include <math.h>

#define HDIM 128
typedef unsigned short u16;
typedef __attribute__((ext_vector_type(8))) short bf16x8;
typedef __attribute__((ext_vector_type(4))) float f32x4;

__device__ __forceinline__ u16 f2bf(float x) {
    unsigned u = __float_as_uint(x);
    u = (u + 0x7FFFu + ((u >> 16) & 1u)) >> 16;
    return (u16)u;
}
__device__ __forceinline__ float bf2f(u16 h) {
    return __uint_as_float(((unsigned)h) << 16);
}
__device__ __forceinline__ bf16x8 ld8(const u16* p) {
    return *reinterpret_cast<const bf16x8*>(p);
}
__device__ __forceinline__ void split8(const float* v, bf16x8& hi, bf16x8& lo) {
#pragma unroll
    for (int j = 0; j < 8; ++j) {
        unsigned u = __float_as_uint(v[j]);
        unsigned h = (u + 0x7FFFu + ((u >> 16) & 1u)) >> 16;
        float rem = v[j] - __uint_as_float(h << 16);
        hi[j] = (short)h;
        lo[j] = (short)(__float_as_uint(rem) >> 16);
    }
}
__device__ __forceinline__ float2 up2(unsigned u) {
    __half2 h = *reinterpret_cast<__half2*>(&u);
    float2 f; f.x = __low2float(h); f.y = __high2float(h); return f;
}
__device__ __forceinline__ u16 f2h(float x) {
    __half t = __float2half(x);
    return *reinterpret_cast<u16*>(&t);
}
__device__ __forceinline__ void acc_u4(float* a, uint4 u, float w) {
    float2 v0 = up2(u.x), v1 = up2(u.y), v2 = up2(u.z), v3 = up2(u.w);
    a[0] = fmaf(w, v0.x, a[0]); a[1] = fmaf(w, v0.y, a[1]);
    a[2] = fmaf(w, v1.x, a[2]); a[3] = fmaf(w, v1.y, a[3]);
    a[4] = fmaf(w, v2.x, a[4]); a[5] = fmaf(w, v2.y, a[5]);
    a[6] = fmaf(w, v3.x, a[6]); a[7] = fmaf(w, v3.y, a[7]);
}
#define MFMA(acc, a, b) acc = __builtin_amdgcn_mfma_f32_16x16x32_bf16(a, b, acc, 0, 0, 0)

// ---------------- weight prep -----------------------------------------------
// Wfull[s][c][k] = dot(Ws[s][k][:], Wih[c][:])  (gi = (hagg@Ws)@Wih^T), hi/lo
__global__ __launch_bounds__(256) void prep_wfull(const float* __restrict__ Ws,
                                                  const float* __restrict__ Wih,
                                                  u16* __restrict__ hi, u16* __restrict__ lo) {
    int s = blockIdx.y;
    int idx = blockIdx.x * 256 + threadIdx.x;   // [0, 49152)
    int c2 = idx >> 7, r = idx & 127;
    const float* wr = Ws + (size_t)s * 16384 + (size_t)r * 128;
    const float* wc = Wih + (size_t)c2 * 128;
    float acc = 0.f;
#pragma unroll 8
    for (int k = 0; k < 128; k += 4) {
        float4 a = *reinterpret_cast<const float4*>(wr + k);
        float4 b = *reinterpret_cast<const float4*>(wc + k);
        acc += a.x * b.x + a.y * b.y + a.z * b.z + a.w * b.w;
    }
    size_t o = (size_t)s * 49152 + idx;
    u16 h = f2bf(acc);
    hi[o] = h; lo[o] = f2bf(acc - bf2f(h));
}

__global__ __launch_bounds__(256) void prep_split(const float* __restrict__ W,
                                                  u16* __restrict__ hi, u16* __restrict__ lo, int n) {
    int i = blockIdx.x * 256 + threadIdx.x;
    if (i < n) { float v = W[i]; u16 h = f2bf(v); hi[i] = h; lo[i] = f2bf(v - bf2f(h)); }
}

// WinT[r][c] = W_in[c][r], [128][64]
__global__ __launch_bounds__(256) void prep_win(const float* __restrict__ W,
                                                u16* __restrict__ hi, u16* __restrict__ lo) {
    int idx = blockIdx.x * 256 + threadIdx.x;        // 0..8191
    int r = idx >> 6, c = idx & 63;
    float v = W[(size_t)c * 128 + r];
    u16 h = f2bf(v);
    hi[idx] = h; lo[idx] = f2bf(v - bf2f(h));
}

// ---------------- embed: Hh = fp16(tanh(X @ Win)), fp32 X read directly -----
__global__ __launch_bounds__(256) void embed_k(const float* __restrict__ X0, const float* __restrict__ X1,
                                               const u16* __restrict__ Bhi0, const u16* __restrict__ Blo0,
                                               const u16* __restrict__ Bhi1, const u16* __restrict__ Blo1,
                                               u16* __restrict__ Hh0, u16* __restrict__ Hh1, int Nn) {
    const int by = blockIdx.y;
    const float* X = by ? X1 : X0;
    const u16* Bhi = by ? Bhi1 : Bhi0;  const u16* Blo = by ? Blo1 : Blo0;
    u16* Hh = by ? Hh1 : Hh0;
    const int tid = threadIdx.x, wave = tid >> 6, lane = tid & 63;
    const int row0 = blockIdx.x * 32, cs = wave * 32;
    const int lr = lane & 15, lk = (lane >> 4) * 8;
    f32x4 acc[2][2];
#pragma unroll
    for (int i = 0; i < 2; ++i)
#pragma unroll
        for (int j = 0; j < 2; ++j) acc[i][j] = (f32x4)0.f;
#pragma unroll
    for (int kc = 0; kc < 2; ++kc) {
        float xv[8];
        bf16x8 ah0, al0, ah1, al1;
        const int r0i = row0 + lr;
        if (r0i < Nn) {
            const float* xp = X + (size_t)r0i * 64 + kc * 32 + lk;
            *reinterpret_cast<float4*>(&xv[0]) = *reinterpret_cast<const float4*>(xp);
            *reinterpret_cast<float4*>(&xv[4]) = *reinterpret_cast<const float4*>(xp + 4);
        } else {
#pragma unroll
            for (int j = 0; j < 8; ++j) xv[j] = 0.f;
        }
        split8(xv, ah0, al0);
        const int r1i = row0 + 16 + lr;
        if (r1i < Nn) {
            const float* xp = X + (size_t)r1i * 64 + kc * 32 + lk;
            *reinterpret_cast<float4*>(&xv[0]) = *reinterpret_cast<const float4*>(xp);
            *reinterpret_cast<float4*>(&xv[4]) = *reinterpret_cast<const float4*>(xp + 4);
        } else {
#pragma unroll
            for (int j = 0; j < 8; ++j) xv[j] = 0.f;
        }
        split8(xv, ah1, al1);
#pragma unroll
        for (int cf = 0; cf < 2; ++cf) {
            const size_t bo = (size_t)(cs + cf * 16 + lr) * 64 + kc * 32 + lk;
            bf16x8 bh = ld8(Bhi + bo), bl = ld8(Blo + bo);
            MFMA(acc[0][cf], ah0, bh); MFMA(acc[0][cf], ah0, bl); MFMA(acc[0][cf], al0, bh);
            MFMA(acc[1][cf], ah1, bh); MFMA(acc[1][cf], ah1, bl); MFMA(acc[1][cf], al1, bh);
        }
    }
#pragma unroll
    for (int rf = 0; rf < 2; ++rf)
#pragma unroll
        for (int cf = 0; cf < 2; ++cf)
#pragma unroll
            for (int rg = 0; rg < 4; ++rg) {
                int row = row0 + rf * 16 + (lane >> 4) * 4 + rg;
                int col = cs + cf * 16 + lr;
                Hh[(size_t)row * HDIM + col] = f2h(tanhf(acc[rf][cf][rg]));
            }
}

// ---------------- fused step: deep-MLP gather, GRU GEMM; 2 graphs -----------
// 512 threads = 8 waves; block covers 32 node-rows of graph blockIdx.y.
// phase 1: wave w gathers nodes w*4..w*4+3; ALL 16 uint4 row-loads issued
//          before any accumulation (one latency window for deg<=16 nodes).
// phase 2: wave w computes cols w*16..w*16+16 of all 6 gate strips via MFMA.
__global__ __launch_bounds__(512, 4) void step_k(const u16* __restrict__ Hh0, const u16* __restrict__ Hh1,
                                                 const int* __restrict__ ro0, const int* __restrict__ ro1,
                                                 const int* __restrict__ ss0, const int* __restrict__ ss1,
                                                 const u16* __restrict__ Wf0h, const u16* __restrict__ Wf0l,
                                                 const u16* __restrict__ Wf1h, const u16* __restrict__ Wf1l,
                                                 const u16* __restrict__ Wh0h, const u16* __restrict__ Wh0l,
                                                 const u16* __restrict__ Wh1h, const u16* __restrict__ Wh1l,
                                                 const float* __restrict__ bi0, const float* __restrict__ bh0,
                                                 const float* __restrict__ bi1, const float* __restrict__ bh1,
                                                 u16* __restrict__ Hn0, u16* __restrict__ Hn1, int Nn) {
    __shared__ u16 agh[32][136];
    __shared__ u16 agl[32][136];
    __shared__ u16 hhh[32][136];
    __shared__ u16 hhl[32][136];
    __shared__ int eidx[1024];
    const int by = blockIdx.y;
    const u16* Hh = by ? Hh1 : Hh0;
    const int* row_off = by ? ro1 : ro0;
    const int* ssrc = by ? ss1 : ss0;
    const int tid = threadIdx.x, wave = tid >> 6, lane = tid & 63;
    const int row0 = blockIdx.x * 32;
    const int g16 = lane >> 4, l16 = lane & 15;

    // ---- phase 0: stage edge indices into LDS ----
    const int rowEnd = (row0 + 32 < Nn) ? row0 + 32 : Nn;
    const int eLo = row_off[row0];
    const int nE = row_off[rowEnd] - eLo;
    for (int i = tid; i < nE && i < 1024; i += 512) eidx[i] = ssrc[eLo + i];
    __syncthreads();

    // ---- phase 1: 4 nodes x 16 edges, all loads in flight ----
    {
        const int nl0 = wave * 4;
        int lo4[4], hi4[4];
#pragma unroll
        for (int q = 0; q < 4; ++q) {
            const int node = row0 + nl0 + q;
            if (node < Nn) {
                lo4[q] = row_off[node] - eLo;
                hi4[q] = row_off[node + 1] - eLo;
            } else { lo4[q] = 0; hi4[q] = 0; }
        }
        uint4 u[4][4];
#pragma unroll
        for (int q = 0; q < 4; ++q)
#pragma unroll
            for (int b = 0; b < 4; ++b) {
                const int p = lo4[q] + b * 4 + g16;
                int idx = 0;
                if (p < hi4[q]) idx = (p < 1024) ? eidx[p] : ssrc[eLo + p];
                u[q][b] = *reinterpret_cast<const uint4*>(Hh + (size_t)idx * HDIM + l16 * 8);
            }
        float a8[4][8];
#pragma unroll
        for (int q = 0; q < 4; ++q) {
#pragma unroll
            for (int j = 0; j < 8; ++j) a8[q][j] = 0.f;
#pragma unroll
            for (int b = 0; b < 4; ++b) {
                const float w = (lo4[q] + b * 4 + g16 < hi4[q]) ? 1.f : 0.f;
                acc_u4(a8[q], u[q][b], w);
            }
            // overflow: deg > 16 (rare, ~10%)
            for (int i = lo4[q] + 16; i < hi4[q]; i += 4) {
                const int p = i + g16;
                const bool val = p < hi4[q];
                int idx = 0;
                if (val) idx = (p < 1024) ? eidx[p] : ssrc[eLo + p];
                uint4 uu = *reinterpret_cast<const uint4*>(Hh + (size_t)idx * HDIM + l16 * 8);
                acc_u4(a8[q], uu, val ? 1.f : 0.f);
            }
        }
#pragma unroll
        for (int q = 0; q < 4; ++q) {
#pragma unroll
            for (int j = 0; j < 8; ++j) {
                a8[q][j] += __shfl_xor(a8[q][j], 16);
                a8[q][j] += __shfl_xor(a8[q][j], 32);
            }
            if (g16 == 0) {
                bf16x8 h8, l8;
                split8(a8[q], h8, l8);
                *reinterpret_cast<bf16x8*>(&agh[nl0 + q][l16 * 8]) = h8;
                *reinterpret_cast<bf16x8*>(&agl[nl0 + q][l16 * 8]) = l8;
            }
        }
    }

    // ---- phase 1c: stage own h rows (fp16 exact), split -> bf16 hi/lo LDS ----
    {
        const int r = tid >> 4, c0 = (tid & 15) * 8;
        float v[8];
        const int row = row0 + r;
        if (row < Nn) {
            const u16* hp = Hh + (size_t)row * HDIM + c0;
#pragma unroll
            for (int j = 0; j < 4; ++j) {
                float2 f = up2(*reinterpret_cast<const unsigned*>(hp + j * 2));
                v[j * 2] = f.x; v[j * 2 + 1] = f.y;
            }
        } else {
#pragma unroll
            for (int j = 0; j < 8; ++j) v[j] = 0.f;
        }
        bf16x8 hi, lo;
        split8(v, hi, lo);
        *reinterpret_cast<bf16x8*>(&hhh[r][c0]) = hi;
        *reinterpret_cast<bf16x8*>(&hhl[r][c0]) = lo;
    }
    __syncthreads();

    // ---- phase 2: GEMM + gates; wave owns 16 cols (cs), 32 rows ----
    const u16* Wfhi = by ? Wf1h : Wf0h;  const u16* Wflo = by ? Wf1l : Wf0l;
    const u16* Whhi = by ? Wh1h : Wh0h;  const u16* Whlo = by ? Wh1l : Wh0l;
    const float* bih = by ? bi1 : bi0;   const float* bhh = by ? bh1 : bh0;
    u16* Hnh = by ? Hn1 : Hn0;
    const int lr = lane & 15, lk = (lane >> 4) * 8, cs = wave * 16;
    f32x4 accI[2][3], accH[2][3];
#pragma unroll
    for (int rf = 0; rf < 2; ++rf)
#pragma unroll
        for (int g = 0; g < 3; ++g) { accI[rf][g] = (f32x4)0.f; accH[rf][g] = (f32x4)0.f; }
#pragma unroll
    for (int kc = 0; kc < 4; ++kc) {
        bf16x8 ga[2], gl[2], ha[2], hl[2];
#pragma unroll
        for (int rf = 0; rf < 2; ++rf) {
            const int rr = rf * 16 + lr, cc = kc * 32 + lk;
            ga[rf] = *reinterpret_cast<const bf16x8*>(&agh[rr][cc]);
            gl[rf] = *reinterpret_cast<const bf16x8*>(&agl[rr][cc]);
            ha[rf] = *reinterpret_cast<const bf16x8*>(&hhh[rr][cc]);
            hl[rf] = *reinterpret_cast<const bf16x8*>(&hhl[rr][cc]);
        }
#pragma unroll
        for (int g = 0; g < 3; ++g) {
            const size_t bo = (size_t)(g * 128 + cs + lr) * HDIM + kc * 32 + lk;
            bf16x8 fh = ld8(Wfhi + bo), fl = ld8(Wflo + bo);
            bf16x8 wh = ld8(Whhi + bo), wl = ld8(Whlo + bo);
#pragma unroll
            for (int rf = 0; rf < 2; ++rf) {
                MFMA(accI[rf][g], ga[rf], fh); MFMA(accI[rf][g], ga[rf], fl); MFMA(accI[rf][g], gl[rf], fh);
                MFMA(accH[rf][g], ha[rf], wh); MFMA(accH[rf][g], ha[rf], wl); MFMA(accH[rf][g], hl[rf], wh);
            }
        }
    }
    const int c = cs + lr;
    const float bir = bih[c], biz = bih[128 + c], bin = bih[256 + c];
    const float bhr = bhh[c], bhz = bhh[128 + c], bhn = bhh[256 + c];
#pragma unroll
    for (int rf = 0; rf < 2; ++rf)
#pragma unroll
        for (int rg = 0; rg < 4; ++rg) {
            const int rl = rf * 16 + (lane >> 4) * 4 + rg;
            const int row = row0 + rl;
            float gir = accI[rf][0][rg] + bir;
            float giz = accI[rf][1][rg] + biz;
            float gin = accI[rf][2][rg] + bin;
            float ghr = accH[rf][0][rg] + bhr;
            float ghz = accH[rf][1][rg] + bhz;
            float ghn = accH[rf][2][rg] + bhn;
            float r = 1.f / (1.f + expf(-(gir + ghr)));
            float z = 1.f / (1.f + expf(-(giz + ghz)));
            float nn = tanhf(gin + r * ghn);
            float hold = bf2f(hhh[rl][c]) + bf2f(hhl[rl][c]);
            float hn = (1.f - z) * nn + z * hold;
            if (row < Nn) Hnh[(size_t)row * HDIM + c] = f2h(hn);
        }
}

// ---------------- CSR build (both graphs via blockIdx.y) --------------------
__global__ void zero_int2(int* p0, int* p1, int n) {
    int i = blockIdx.x * 256 + threadIdx.x;
    int* p = blockIdx.y ? p1 : p0;
    if (i < n) p[i] = 0;
}

__global__ void hist_k2(const int* __restrict__ d0, const int* __restrict__ d1,
                        int* __restrict__ c0, int* __restrict__ c1, int E) {
    int e = blockIdx.x * 256 + threadIdx.x;
    const int* dst = blockIdx.y ? d1 : d0;
    int* cnt = blockIdx.y ? c1 : c0;
    if (e < E) atomicAdd(&cnt[dst[e]], 1);
}

// parallel scan, 3 phases. A: per-block (1024 elems) partial scan + block total.
__global__ __launch_bounds__(256) void scan_part(const int* __restrict__ c0, const int* __restrict__ c1,
                                                 int* __restrict__ r0, int* __restrict__ r1,
                                                 int* __restrict__ bt0, int* __restrict__ bt1, int n) {
    const int* cnt = blockIdx.y ? c1 : c0;
    int* ro = blockIdx.y ? r1 : r0;
    int* bt = blockIdx.y ? bt1 : bt0;
    __shared__ int wsum[4];
    const int tid = threadIdx.x, lane = tid & 63, wv = tid >> 6;
    const int i0 = blockIdx.x * 1024 + tid * 4;
    int v[4];
#pragma unroll
    for (int j = 0; j < 4; ++j) v[j] = (i0 + j < n) ? cnt[i0 + j] : 0;
    int s = v[0] + v[1] + v[2] + v[3];
    int x = s;
#pragma unroll
    for (int off = 1; off < 64; off <<= 1) { int t = __shfl_up(x, off); if (lane >= off) x += t; }
    if (lane == 63) wsum[wv] = x;
    __syncthreads();
    int wbase = 0;
#pragma unroll
    for (int w = 0; w < 4; ++w) wbase += (w < wv) ? wsum[w] : 0;
    int run = wbase + x - s;
#pragma unroll
    for (int j = 0; j < 4; ++j) { if (i0 + j < n) ro[i0 + j] = run; run += v[j]; }
    if (tid == 255) bt[blockIdx.x] = wbase + x;
}

// B: exclusive-scan the block totals (nb <= 64); bt[nb] = grand total.
__global__ void scan_tops(int* __restrict__ bt0, int* __restrict__ bt1, int nb) {
    int* bt = blockIdx.x ? bt1 : bt0;
    const int lane = threadIdx.x;   // 64 threads
    int v = (lane < nb) ? bt[lane] : 0;
    int x = v;
#pragma unroll
    for (int off = 1; off < 64; off <<= 1) { int t = __shfl_up(x, off); if (lane >= off) x += t; }
    if (lane < nb) bt[lane] = x - v;
    if (lane == 63) bt[nb] = x;
}

// C: add block offsets; write cursor copy and row_off[n].
__global__ void scan_fix(int* __restrict__ r0, int* __restrict__ r1,
                         const int* __restrict__ bt0, const int* __restrict__ bt1,
                         int* __restrict__ cur0, int* __restrict__ cur1, int n, int nb) {
    const int i = blockIdx.x * 256 + threadIdx.x;
    int* ro = blockIdx.y ? r1 : r0;
    const int* bt = blockIdx.y ? bt1 : bt0;
    int* cur = blockIdx.y ? cur1 : cur0;
    if (i < n) {
        int val = ro[i] + bt[i >> 10];
        ro[i] = val;
        cur[i] = val;
    } else if (i == n) {
        ro[n] = bt[nb];
    }
}

__global__ void scatter_k2(const int* __restrict__ s0, const int* __restrict__ d0,
                           const int* __restrict__ s1, const int* __restrict__ d1,
                           int* __restrict__ c0, int* __restrict__ c1,
                           int* __restrict__ o0, int* __restrict__ o1, int E) {
    int e = blockIdx.x * 256 + threadIdx.x;
    const int* src = blockIdx.y ? s1 : s0;
    const int* dst = blockIdx.y ? d1 : d0;
    int* cursor = blockIdx.y ? c1 : c0;
    int* ssrc = blockIdx.y ? o1 : o0;
    if (e < E) {
        int p = atomicAdd(&cursor[dst[e]], 1);
        ssrc[p] = src[e];
    }
}

// ---------------- mean-pool + relu (both graphs, fp16 input) ----------------
__global__ __launch_bounds__(256) void pool_k(const u16* __restrict__ H0, const u16* __restrict__ H1,
                                              const int* __restrict__ batch,
                                              float* __restrict__ p0, float* __restrict__ p1, int M) {
    const u16* Hf = blockIdx.y ? H1 : H0;
    float* pooled = blockIdx.y ? p1 : p0;
    __shared__ int lo_s, hi_s;
    __shared__ float smx[256], smy[256];
    int g = blockIdx.x;
    if (threadIdx.x == 0) {
        int lo = 0, hi = M;
        while (lo < hi) { int mid = (lo + hi) >> 1; if (batch[mid] < g) lo = mid + 1; else hi = mid; }
        lo_s = lo;
        int lo2 = lo, hi2 = M;
        while (lo2 < hi2) { int mid = (lo2 + hi2) >> 1; if (batch[mid] < g + 1) lo2 = mid + 1; else hi2 = mid; }
        hi_s = lo2;
    }
    __syncthreads();
    int lo = lo_s, hi = hi_s;
    int c2 = threadIdx.x & 63, quarter = threadIdx.x >> 6;
    float ax = 0.f, ay = 0.f;
    for (int i = lo + quarter; i < hi; i += 4) {
        float2 v = up2(*reinterpret_cast<const unsigned*>(Hf + (size_t)i * HDIM + c2 * 2));
        ax += v.x; ay += v.y;
    }
    smx[threadIdx.x] = ax; smy[threadIdx.x] = ay;
    __syncthreads();
    if (quarter == 0) {
        float sx = smx[c2] + smx[c2 + 64] + smx[c2 + 128] + smx[c2 + 192];
        float sy = smy[c2] + smy[c2 + 64] + smy[c2 + 128] + smy[c2 + 192];
        float cnt = (float)(hi - lo); if (cnt < 1.f) cnt = 1.f;
        pooled[g * HDIM + c2 * 2]     = fmaxf(sx / cnt, 0.f);
        pooled[g * HDIM + c2 * 2 + 1] = fmaxf(sy / cnt, 0.f);
    }
}

// ---------------- prediction head -------------------------------------------
__global__ void pred_kernel(const float* __restrict__ pa, const float* __restrict__ pv,
                            const float* __restrict__ pW, const float* __restrict__ pb,
                            float* __restrict__ out) {
    int g = blockIdx.x, lane = threadIdx.x; // 64 threads
    float s = pa[g * HDIM + lane] * pW[lane]
            + pa[g * HDIM + 64 + lane] * pW[64 + lane]
            + pv[g * HDIM + lane] * pW[HDIM + lane]
            + pv[g * HDIM + 64 + lane] * pW[192 + lane];
    for (int off = 32; off; off >>= 1) s += __shfl_down(s, off);
    if (lane == 0) out[g] = s + pb[0];
}

extern "C" void kernel_launch(void* const* d_in, const int* in_sizes, int n_in,
                              void* d_out, int out_size, void* d_ws, size_t ws_size,
                              hipStream_t stream) {
    const float* atom_x   = (const float*)d_in[0];
    const float* voro_x   = (const float*)d_in[1];
    const int*   atom_ei  = (const int*)d_in[2];
    const int*   voro_ei  = (const int*)d_in[3];
    const int*   batch    = (const int*)d_in[4];
    const float* W_at_in  = (const float*)d_in[5];
    const float* W_vo_in  = (const float*)d_in[6];
    const float* atom_W   = (const float*)d_in[7];
    const float* voro_W   = (const float*)d_in[8];
    const float* atom_Wih = (const float*)d_in[9];
    const float* atom_Whh = (const float*)d_in[10];
    const float* atom_bih = (const float*)d_in[11];
    const float* atom_bhh = (const float*)d_in[12];
    const float* voro_Wih = (const float*)d_in[13];
    const float* voro_Whh = (const float*)d_in[14];
    const float* voro_bih = (const float*)d_in[15];
    const float* voro_bhh = (const float*)d_in[16];
    const float* pred_W   = (const float*)d_in[17];
    const float* pred_b   = (const float*)d_in[18];
    float* out = (float*)d_out;

    const int Nn = in_sizes[4];
    const int Ee = in_sizes[2] / 2;
    const int Gg = out_size;
    const int Npad = (Nn + 31) & ~31;
    const int nbScan = (Nn + 1023) / 1024;

    char* base = (char*)d_ws;
    size_t off = 0;
    auto alloc = [&](size_t bytes) -> char* {
        char* p = base + off;
        off = (off + bytes + 255) & ~(size_t)255;
        return p;
    };

    u16 *HhA[2], *HhB[2];
    u16 *WfHi[2], *WfLo[2], *WhHi[2], *WhLo[2], *WnHi[2], *WnLo[2];
    int *row_off[2], *cursor[2], *ssrc[2], *bt[2];
    for (int t = 0; t < 2; ++t) {
        HhA[t] = (u16*)alloc((size_t)Npad * HDIM * 2);
        HhB[t] = (u16*)alloc((size_t)Npad * HDIM * 2);
        WfHi[t] = (u16*)alloc(4 * 49152 * 2); WfLo[t] = (u16*)alloc(4 * 49152 * 2);
        WhHi[t] = (u16*)alloc(384 * 128 * 2); WhLo[t] = (u16*)alloc(384 * 128 * 2);
        WnHi[t] = (u16*)alloc(128 * 64 * 2);  WnLo[t] = (u16*)alloc(128 * 64 * 2);
        row_off[t] = (int*)alloc((size_t)(Nn + 1) * 4);
        cursor[t]  = (int*)alloc((size_t)Nn * 4);
        ssrc[t]    = (int*)alloc((size_t)Ee * 4);
        bt[t]      = (int*)alloc((size_t)(nbScan + 1) * 4);
    }
    float* pooledA = (float*)alloc((size_t)Gg * HDIM * 4);
    float* pooledV = (float*)alloc((size_t)Gg * HDIM * 4);

    const float* Wst[2] = {atom_W, voro_W};
    const float* Wih[2] = {atom_Wih, voro_Wih};
    const float* Whh[2] = {atom_Whh, voro_Whh};
    const float* Win[2] = {W_at_in, W_vo_in};

    for (int t = 0; t < 2; ++t) {
        prep_wfull<<<dim3(192, 4), 256, 0, stream>>>(Wst[t], Wih[t], WfHi[t], WfLo[t]);
        prep_split<<<192, 256, 0, stream>>>(Whh[t], WhHi[t], WhLo[t], 384 * 128);
        prep_win<<<32, 256, 0, stream>>>(Win[t], WnHi[t], WnLo[t]);
    }

    const int eb  = (Ee + 255) / 256;
    const int nb  = (Nn + 255) / 256;
    const int gbs = Npad / 32;

    embed_k<<<dim3(gbs, 2), 256, 0, stream>>>(atom_x, voro_x,
                                              WnHi[0], WnLo[0], WnHi[1], WnLo[1],
                                              HhA[0], HhA[1], Nn);

    zero_int2<<<dim3(nb, 2), 256, 0, stream>>>(cursor[0], cursor[1], Nn);
    hist_k2<<<dim3(eb, 2), 256, 0, stream>>>(atom_ei + Ee, voro_ei + Ee, cursor[0], cursor[1], Ee);
    scan_part<<<dim3(nbScan, 2), 256, 0, stream>>>(cursor[0], cursor[1], row_off[0], row_off[1],
                                                   bt[0], bt[1], Nn);
    scan_tops<<<2, 64, 0, stream>>>(bt[0], bt[1], nbScan);
    scan_fix<<<dim3((Nn + 1 + 255) / 256, 2), 256, 0, stream>>>(row_off[0], row_off[1], bt[0], bt[1],
                                                                cursor[0], cursor[1], Nn, nbScan);
    scatter_k2<<<dim3(eb, 2), 256, 0, stream>>>(atom_ei, atom_ei + Ee, voro_ei, voro_ei + Ee,
                                                cursor[0], cursor[1], ssrc[0], ssrc[1], Ee);

    u16 *gA0 = HhA[0], *gB0 = HhB[0], *gA1 = HhA[1], *gB1 = HhB[1];
    for (int s = 0; s < 4; ++s) {
        step_k<<<dim3(gbs, 2), 512, 0, stream>>>(
            gA0, gA1, row_off[0], row_off[1], ssrc[0], ssrc[1],
            WfHi[0] + (size_t)s * 49152, WfLo[0] + (size_t)s * 49152,
            WfHi[1] + (size_t)s * 49152, WfLo[1] + (size_t)s * 49152,
            WhHi[0], WhLo[0], WhHi[1], WhLo[1],
            atom_bih, atom_bhh, voro_bih, voro_bhh,
            gB0, gB1, Nn);
        u16* up;
        up = gA0; gA0 = gB0; gB0 = up;
        up = gA1; gA1 = gB1; gB1 = up;
    }
    pool_k<<<dim3(Gg, 2), 256, 0, stream>>>(gA0, gA1, batch, pooledA, pooledV, Nn);
    pred_kernel<<<Gg, 64, 0, stream>>>(pooledA, pooledV, pred_W, pred_b, out);
}

// Round 15
// 1062.113 us; speedup vs baseline: 1.5088x; 1.0344x over previous
//
#include <hip/hip_runtime.h>
#include <hip/hip_fp16.h>
#include <math.h>

#define HDIM 128
typedef unsigned short u16;
typedef __attribute__((ext_vector_type(8))) short bf16x8;
typedef __attribute__((ext_vector_type(4))) float f32x4;

__device__ __forceinline__ u16 f2bf(float x) {
    unsigned u = __float_as_uint(x);
    u = (u + 0x7FFFu + ((u >> 16) & 1u)) >> 16;
    return (u16)u;
}
__device__ __forceinline__ float bf2f(u16 h) {
    return __uint_as_float(((unsigned)h) << 16);
}
__device__ __forceinline__ bf16x8 ld8(const u16* p) {
    return *reinterpret_cast<const bf16x8*>(p);
}
__device__ __forceinline__ void split8(const float* v, bf16x8& hi, bf16x8& lo) {
#pragma unroll
    for (int j = 0; j < 8; ++j) {
        unsigned u = __float_as_uint(v[j]);
        unsigned h = (u + 0x7FFFu + ((u >> 16) & 1u)) >> 16;
        float rem = v[j] - __uint_as_float(h << 16);
        hi[j] = (short)h;
        lo[j] = (short)(__float_as_uint(rem) >> 16);
    }
}
__device__ __forceinline__ float2 up2(unsigned u) {
    __half2 h = *reinterpret_cast<__half2*>(&u);
    float2 f; f.x = __low2float(h); f.y = __high2float(h); return f;
}
__device__ __forceinline__ u16 f2h(float x) {
    __half t = __float2half(x);
    return *reinterpret_cast<u16*>(&t);
}
__device__ __forceinline__ void acc_u4(float* a, uint4 u, float w) {
    float2 v0 = up2(u.x), v1 = up2(u.y), v2 = up2(u.z), v3 = up2(u.w);
    a[0] = fmaf(w, v0.x, a[0]); a[1] = fmaf(w, v0.y, a[1]);
    a[2] = fmaf(w, v1.x, a[2]); a[3] = fmaf(w, v1.y, a[3]);
    a[4] = fmaf(w, v2.x, a[4]); a[5] = fmaf(w, v2.y, a[5]);
    a[6] = fmaf(w, v3.x, a[6]); a[7] = fmaf(w, v3.y, a[7]);
}
#define MFMA(acc, a, b) acc = __builtin_amdgcn_mfma_f32_16x16x32_bf16(a, b, acc, 0, 0, 0)

// ---------------- weight prep (both graphs via blockIdx.z / y) --------------
// Wfull[s][c][k] = dot(Ws[s][k][:], Wih[c][:]), hi/lo split
__global__ __launch_bounds__(256) void prep_wfull(const float* __restrict__ Ws0, const float* __restrict__ Wi0,
                                                  const float* __restrict__ Ws1, const float* __restrict__ Wi1,
                                                  u16* __restrict__ hi0, u16* __restrict__ lo0,
                                                  u16* __restrict__ hi1, u16* __restrict__ lo1) {
    const int gz = blockIdx.z;
    const float* Ws = gz ? Ws1 : Ws0;
    const float* Wih = gz ? Wi1 : Wi0;
    u16* hi = gz ? hi1 : hi0;
    u16* lo = gz ? lo1 : lo0;
    int s = blockIdx.y;
    int idx = blockIdx.x * 256 + threadIdx.x;   // [0, 49152)
    int c2 = idx >> 7, r = idx & 127;
    const float* wr = Ws + (size_t)s * 16384 + (size_t)r * 128;
    const float* wc = Wih + (size_t)c2 * 128;
    float acc = 0.f;
#pragma unroll 8
    for (int k = 0; k < 128; k += 4) {
        float4 a = *reinterpret_cast<const float4*>(wr + k);
        float4 b = *reinterpret_cast<const float4*>(wc + k);
        acc += a.x * b.x + a.y * b.y + a.z * b.z + a.w * b.w;
    }
    size_t o = (size_t)s * 49152 + idx;
    u16 h = f2bf(acc);
    hi[o] = h; lo[o] = f2bf(acc - bf2f(h));
}

__global__ __launch_bounds__(256) void prep_split2(const float* __restrict__ W0, const float* __restrict__ W1,
                                                   u16* __restrict__ hi0, u16* __restrict__ lo0,
                                                   u16* __restrict__ hi1, u16* __restrict__ lo1, int n) {
    const float* W = blockIdx.y ? W1 : W0;
    u16* hi = blockIdx.y ? hi1 : hi0;
    u16* lo = blockIdx.y ? lo1 : lo0;
    int i = blockIdx.x * 256 + threadIdx.x;
    if (i < n) { float v = W[i]; u16 h = f2bf(v); hi[i] = h; lo[i] = f2bf(v - bf2f(h)); }
}

// WinT[r][c] = W_in[c][r], [128][64]
__global__ __launch_bounds__(256) void prep_win2(const float* __restrict__ W0, const float* __restrict__ W1,
                                                 u16* __restrict__ hi0, u16* __restrict__ lo0,
                                                 u16* __restrict__ hi1, u16* __restrict__ lo1) {
    const float* W = blockIdx.y ? W1 : W0;
    u16* hi = blockIdx.y ? hi1 : hi0;
    u16* lo = blockIdx.y ? lo1 : lo0;
    int idx = blockIdx.x * 256 + threadIdx.x;        // 0..8191
    int r = idx >> 6, c = idx & 63;
    float v = W[(size_t)c * 128 + r];
    u16 h = f2bf(v);
    hi[idx] = h; lo[idx] = f2bf(v - bf2f(h));
}

// ---------------- embed: Hh = fp16(tanh(X @ Win)), fp32 X read directly -----
__global__ __launch_bounds__(256) void embed_k(const float* __restrict__ X0, const float* __restrict__ X1,
                                               const u16* __restrict__ Bhi0, const u16* __restrict__ Blo0,
                                               const u16* __restrict__ Bhi1, const u16* __restrict__ Blo1,
                                               u16* __restrict__ Hh0, u16* __restrict__ Hh1, int Nn) {
    const int by = blockIdx.y;
    const float* X = by ? X1 : X0;
    const u16* Bhi = by ? Bhi1 : Bhi0;  const u16* Blo = by ? Blo1 : Blo0;
    u16* Hh = by ? Hh1 : Hh0;
    const int tid = threadIdx.x, wave = tid >> 6, lane = tid & 63;
    const int row0 = blockIdx.x * 32, cs = wave * 32;
    const int lr = lane & 15, lk = (lane >> 4) * 8;
    f32x4 acc[2][2];
#pragma unroll
    for (int i = 0; i < 2; ++i)
#pragma unroll
        for (int j = 0; j < 2; ++j) acc[i][j] = (f32x4)0.f;
#pragma unroll
    for (int kc = 0; kc < 2; ++kc) {
        float xv[8];
        bf16x8 ah0, al0, ah1, al1;
        const int r0i = row0 + lr;
        if (r0i < Nn) {
            const float* xp = X + (size_t)r0i * 64 + kc * 32 + lk;
            *reinterpret_cast<float4*>(&xv[0]) = *reinterpret_cast<const float4*>(xp);
            *reinterpret_cast<float4*>(&xv[4]) = *reinterpret_cast<const float4*>(xp + 4);
        } else {
#pragma unroll
            for (int j = 0; j < 8; ++j) xv[j] = 0.f;
        }
        split8(xv, ah0, al0);
        const int r1i = row0 + 16 + lr;
        if (r1i < Nn) {
            const float* xp = X + (size_t)r1i * 64 + kc * 32 + lk;
            *reinterpret_cast<float4*>(&xv[0]) = *reinterpret_cast<const float4*>(xp);
            *reinterpret_cast<float4*>(&xv[4]) = *reinterpret_cast<const float4*>(xp + 4);
        } else {
#pragma unroll
            for (int j = 0; j < 8; ++j) xv[j] = 0.f;
        }
        split8(xv, ah1, al1);
#pragma unroll
        for (int cf = 0; cf < 2; ++cf) {
            const size_t bo = (size_t)(cs + cf * 16 + lr) * 64 + kc * 32 + lk;
            bf16x8 bh = ld8(Bhi + bo), bl = ld8(Blo + bo);
            MFMA(acc[0][cf], ah0, bh); MFMA(acc[0][cf], ah0, bl); MFMA(acc[0][cf], al0, bh);
            MFMA(acc[1][cf], ah1, bh); MFMA(acc[1][cf], ah1, bl); MFMA(acc[1][cf], al1, bh);
        }
    }
#pragma unroll
    for (int rf = 0; rf < 2; ++rf)
#pragma unroll
        for (int cf = 0; cf < 2; ++cf)
#pragma unroll
            for (int rg = 0; rg < 4; ++rg) {
                int row = row0 + rf * 16 + (lane >> 4) * 4 + rg;
                int col = cs + cf * 16 + lr;
                Hh[(size_t)row * HDIM + col] = f2h(tanhf(acc[rf][cf][rg]));
            }
}

// ---------------- fused step: shuffle-indexed gather, GRU GEMM; 2 graphs ----
// 512 threads = 8 waves; block covers 32 node-rows of graph blockIdx.y.
// phase 1 (fast path, ~97% of waves): wave's 4 nodes own a contiguous CSR
//   range <= 64 edges; indices come from ONE coalesced ssrc load + __shfl,
//   so all 16 uint4 row-loads have register-only address deps -> issued
//   back-to-back in a single latency window.
// phase 2: wave w computes cols w*16..w*16+16 of all 6 gate strips via MFMA.
__global__ __launch_bounds__(512, 4) void step_k(const u16* __restrict__ Hh0, const u16* __restrict__ Hh1,
                                                 const int* __restrict__ ro0, const int* __restrict__ ro1,
                                                 const int* __restrict__ ss0, const int* __restrict__ ss1,
                                                 const u16* __restrict__ Wf0h, const u16* __restrict__ Wf0l,
                                                 const u16* __restrict__ Wf1h, const u16* __restrict__ Wf1l,
                                                 const u16* __restrict__ Wh0h, const u16* __restrict__ Wh0l,
                                                 const u16* __restrict__ Wh1h, const u16* __restrict__ Wh1l,
                                                 const float* __restrict__ bi0, const float* __restrict__ bh0,
                                                 const float* __restrict__ bi1, const float* __restrict__ bh1,
                                                 u16* __restrict__ Hn0, u16* __restrict__ Hn1, int Nn) {
    __shared__ u16 agh[32][136];
    __shared__ u16 agl[32][136];
    __shared__ u16 hhh[32][136];
    __shared__ u16 hhl[32][136];
    const int by = blockIdx.y;
    const u16* Hh = by ? Hh1 : Hh0;
    const int* row_off = by ? ro1 : ro0;
    const int* ssrc = by ? ss1 : ss0;
    const int tid = threadIdx.x, wave = tid >> 6, lane = tid & 63;
    const int row0 = blockIdx.x * 32;
    const int g16 = lane >> 4, l16 = lane & 15;

    // ---- phase 1: 4 nodes per wave, shuffle-distributed indices ----
    {
        const int nl0 = wave * 4;
        int lo4[4], hi4[4];
#pragma unroll
        for (int q = 0; q < 4; ++q) {
            const int node = row0 + nl0 + q;
            if (node < Nn) {
                lo4[q] = row_off[node];
                hi4[q] = row_off[node + 1];
            } else { lo4[q] = 0; hi4[q] = 0; }
        }
        const int wbase = lo4[0];
        const int wtot = hi4[3] - wbase;
        // one coalesced index load for the wave's whole edge window
        const int myidx = ssrc[wbase + lane];
        float a8[4][8];
        if (wtot <= 64 && hi4[3] > 0) {
            uint4 u[4][4];
#pragma unroll
            for (int q = 0; q < 4; ++q)
#pragma unroll
                for (int b = 0; b < 4; ++b) {
                    const int p = lo4[q] + b * 4 + g16;
                    int idx = __shfl(myidx, p - wbase);
                    idx = (p < hi4[q]) ? idx : 0;
                    u[q][b] = *reinterpret_cast<const uint4*>(Hh + (size_t)idx * HDIM + l16 * 8);
                }
#pragma unroll
            for (int q = 0; q < 4; ++q) {
#pragma unroll
                for (int j = 0; j < 8; ++j) a8[q][j] = 0.f;
#pragma unroll
                for (int b = 0; b < 4; ++b) {
                    const float w = (lo4[q] + b * 4 + g16 < hi4[q]) ? 1.f : 0.f;
                    acc_u4(a8[q], u[q][b], w);
                }
                // deg > 16 overflow (still inside the 64-window)
                for (int i = lo4[q] + 16; i < hi4[q]; i += 4) {
                    const int p = i + g16;
                    const bool val = p < hi4[q];
                    int idx = __shfl(myidx, p - wbase);
                    idx = val ? idx : 0;
                    uint4 uu = *reinterpret_cast<const uint4*>(Hh + (size_t)idx * HDIM + l16 * 8);
                    acc_u4(a8[q], uu, val ? 1.f : 0.f);
                }
            }
        } else {
            // slow path (~3% of waves): direct ssrc-indexed bursts
#pragma unroll
            for (int q = 0; q < 4; ++q) {
#pragma unroll
                for (int j = 0; j < 8; ++j) a8[q][j] = 0.f;
                for (int i = lo4[q]; i < hi4[q]; i += 4) {
                    const int p = i + g16;
                    const bool val = p < hi4[q];
                    const int idx = val ? ssrc[p] : 0;
                    uint4 uu = *reinterpret_cast<const uint4*>(Hh + (size_t)idx * HDIM + l16 * 8);
                    acc_u4(a8[q], uu, val ? 1.f : 0.f);
                }
            }
        }
#pragma unroll
        for (int q = 0; q < 4; ++q) {
#pragma unroll
            for (int j = 0; j < 8; ++j) {
                a8[q][j] += __shfl_xor(a8[q][j], 16);
                a8[q][j] += __shfl_xor(a8[q][j], 32);
            }
            if (g16 == 0) {
                bf16x8 h8, l8;
                split8(a8[q], h8, l8);
                *reinterpret_cast<bf16x8*>(&agh[nl0 + q][l16 * 8]) = h8;
                *reinterpret_cast<bf16x8*>(&agl[nl0 + q][l16 * 8]) = l8;
            }
        }
    }

    // ---- phase 1c: stage own h rows (fp16 exact), split -> bf16 hi/lo LDS ----
    {
        const int r = tid >> 4, c0 = (tid & 15) * 8;
        float v[8];
        const int row = row0 + r;
        if (row < Nn) {
            const u16* hp = Hh + (size_t)row * HDIM + c0;
#pragma unroll
            for (int j = 0; j < 4; ++j) {
                float2 f = up2(*reinterpret_cast<const unsigned*>(hp + j * 2));
                v[j * 2] = f.x; v[j * 2 + 1] = f.y;
            }
        } else {
#pragma unroll
            for (int j = 0; j < 8; ++j) v[j] = 0.f;
        }
        bf16x8 hi, lo;
        split8(v, hi, lo);
        *reinterpret_cast<bf16x8*>(&hhh[r][c0]) = hi;
        *reinterpret_cast<bf16x8*>(&hhl[r][c0]) = lo;
    }
    __syncthreads();

    // ---- phase 2: GEMM + gates; wave owns 16 cols (cs), 32 rows ----
    const u16* Wfhi = by ? Wf1h : Wf0h;  const u16* Wflo = by ? Wf1l : Wf0l;
    const u16* Whhi = by ? Wh1h : Wh0h;  const u16* Whlo = by ? Wh1l : Wh0l;
    const float* bih = by ? bi1 : bi0;   const float* bhh = by ? bh1 : bh0;
    u16* Hnh = by ? Hn1 : Hn0;
    const int lr = lane & 15, lk = (lane >> 4) * 8, cs = wave * 16;
    f32x4 accI[2][3], accH[2][3];
#pragma unroll
    for (int rf = 0; rf < 2; ++rf)
#pragma unroll
        for (int g = 0; g < 3; ++g) { accI[rf][g] = (f32x4)0.f; accH[rf][g] = (f32x4)0.f; }
#pragma unroll
    for (int kc = 0; kc < 4; ++kc) {
        bf16x8 ga[2], gl[2], ha[2], hl[2];
#pragma unroll
        for (int rf = 0; rf < 2; ++rf) {
            const int rr = rf * 16 + lr, cc = kc * 32 + lk;
            ga[rf] = *reinterpret_cast<const bf16x8*>(&agh[rr][cc]);
            gl[rf] = *reinterpret_cast<const bf16x8*>(&agl[rr][cc]);
            ha[rf] = *reinterpret_cast<const bf16x8*>(&hhh[rr][cc]);
            hl[rf] = *reinterpret_cast<const bf16x8*>(&hhl[rr][cc]);
        }
#pragma unroll
        for (int g = 0; g < 3; ++g) {
            const size_t bo = (size_t)(g * 128 + cs + lr) * HDIM + kc * 32 + lk;
            bf16x8 fh = ld8(Wfhi + bo), fl = ld8(Wflo + bo);
            bf16x8 wh = ld8(Whhi + bo), wl = ld8(Whlo + bo);
#pragma unroll
            for (int rf = 0; rf < 2; ++rf) {
                MFMA(accI[rf][g], ga[rf], fh); MFMA(accI[rf][g], ga[rf], fl); MFMA(accI[rf][g], gl[rf], fh);
                MFMA(accH[rf][g], ha[rf], wh); MFMA(accH[rf][g], ha[rf], wl); MFMA(accH[rf][g], hl[rf], wh);
            }
        }
    }
    const int c = cs + lr;
    const float bir = bih[c], biz = bih[128 + c], bin = bih[256 + c];
    const float bhr = bhh[c], bhz = bhh[128 + c], bhn = bhh[256 + c];
#pragma unroll
    for (int rf = 0; rf < 2; ++rf)
#pragma unroll
        for (int rg = 0; rg < 4; ++rg) {
            const int rl = rf * 16 + (lane >> 4) * 4 + rg;
            const int row = row0 + rl;
            float gir = accI[rf][0][rg] + bir;
            float giz = accI[rf][1][rg] + biz;
            float gin = accI[rf][2][rg] + bin;
            float ghr = accH[rf][0][rg] + bhr;
            float ghz = accH[rf][1][rg] + bhz;
            float ghn = accH[rf][2][rg] + bhn;
            float r = 1.f / (1.f + expf(-(gir + ghr)));
            float z = 1.f / (1.f + expf(-(giz + ghz)));
            float nn = tanhf(gin + r * ghn);
            float hold = bf2f(hhh[rl][c]) + bf2f(hhl[rl][c]);
            float hn = (1.f - z) * nn + z * hold;
            if (row < Nn) Hnh[(size_t)row * HDIM + c] = f2h(hn);
        }
}

// ---------------- CSR build (both graphs via blockIdx.y) --------------------
__global__ void zero_int2(int* p0, int* p1, int n) {
    int i = blockIdx.x * 256 + threadIdx.x;
    int* p = blockIdx.y ? p1 : p0;
    if (i < n) p[i] = 0;
}

__global__ void hist_k2(const int* __restrict__ d0, const int* __restrict__ d1,
                        int* __restrict__ c0, int* __restrict__ c1, int E) {
    int e = blockIdx.x * 256 + threadIdx.x;
    const int* dst = blockIdx.y ? d1 : d0;
    int* cnt = blockIdx.y ? c1 : c0;
    if (e < E) atomicAdd(&cnt[dst[e]], 1);
}

// parallel scan, 3 phases. A: per-block (1024 elems) partial scan + block total.
__global__ __launch_bounds__(256) void scan_part(const int* __restrict__ c0, const int* __restrict__ c1,
                                                 int* __restrict__ r0, int* __restrict__ r1,
                                                 int* __restrict__ bt0, int* __restrict__ bt1, int n) {
    const int* cnt = blockIdx.y ? c1 : c0;
    int* ro = blockIdx.y ? r1 : r0;
    int* bt = blockIdx.y ? bt1 : bt0;
    __shared__ int wsum[4];
    const int tid = threadIdx.x, lane = tid & 63, wv = tid >> 6;
    const int i0 = blockIdx.x * 1024 + tid * 4;
    int v[4];
#pragma unroll
    for (int j = 0; j < 4; ++j) v[j] = (i0 + j < n) ? cnt[i0 + j] : 0;
    int s = v[0] + v[1] + v[2] + v[3];
    int x = s;
#pragma unroll
    for (int off = 1; off < 64; off <<= 1) { int t = __shfl_up(x, off); if (lane >= off) x += t; }
    if (lane == 63) wsum[wv] = x;
    __syncthreads();
    int wbase = 0;
#pragma unroll
    for (int w = 0; w < 4; ++w) wbase += (w < wv) ? wsum[w] : 0;
    int run = wbase + x - s;
#pragma unroll
    for (int j = 0; j < 4; ++j) { if (i0 + j < n) ro[i0 + j] = run; run += v[j]; }
    if (tid == 255) bt[blockIdx.x] = wbase + x;
}

// B: exclusive-scan the block totals (nb <= 64); bt[nb] = grand total.
__global__ void scan_tops(int* __restrict__ bt0, int* __restrict__ bt1, int nb) {
    int* bt = blockIdx.x ? bt1 : bt0;
    const int lane = threadIdx.x;   // 64 threads
    int v = (lane < nb) ? bt[lane] : 0;
    int x = v;
#pragma unroll
    for (int off = 1; off < 64; off <<= 1) { int t = __shfl_up(x, off); if (lane >= off) x += t; }
    if (lane < nb) bt[lane] = x - v;
    if (lane == 63) bt[nb] = x;
}

// C: add block offsets; write cursor copy and row_off[n].
__global__ void scan_fix(int* __restrict__ r0, int* __restrict__ r1,
                         const int* __restrict__ bt0, const int* __restrict__ bt1,
                         int* __restrict__ cur0, int* __restrict__ cur1, int n, int nb) {
    const int i = blockIdx.x * 256 + threadIdx.x;
    int* ro = blockIdx.y ? r1 : r0;
    const int* bt = blockIdx.y ? bt1 : bt0;
    int* cur = blockIdx.y ? cur1 : cur0;
    if (i < n) {
        int val = ro[i] + bt[i >> 10];
        ro[i] = val;
        cur[i] = val;
    } else if (i == n) {
        ro[n] = bt[nb];
    }
}

__global__ void scatter_k2(const int* __restrict__ s0, const int* __restrict__ d0,
                           const int* __restrict__ s1, const int* __restrict__ d1,
                           int* __restrict__ c0, int* __restrict__ c1,
                           int* __restrict__ o0, int* __restrict__ o1, int E) {
    int e = blockIdx.x * 256 + threadIdx.x;
    const int* src = blockIdx.y ? s1 : s0;
    const int* dst = blockIdx.y ? d1 : d0;
    int* cursor = blockIdx.y ? c1 : c0;
    int* ssrc = blockIdx.y ? o1 : o0;
    if (e < E) {
        int p = atomicAdd(&cursor[dst[e]], 1);
        ssrc[p] = src[e];
    }
}

// ---------------- mean-pool + relu (both graphs, fp16 input) ----------------
__global__ __launch_bounds__(256) void pool_k(const u16* __restrict__ H0, const u16* __restrict__ H1,
                                              const int* __restrict__ batch,
                                              float* __restrict__ p0, float* __restrict__ p1, int M) {
    const u16* Hf = blockIdx.y ? H1 : H0;
    float* pooled = blockIdx.y ? p1 : p0;
    __shared__ int lo_s, hi_s;
    __shared__ float smx[256], smy[256];
    int g = blockIdx.x;
    if (threadIdx.x == 0) {
        int lo = 0, hi = M;
        while (lo < hi) { int mid = (lo + hi) >> 1; if (batch[mid] < g) lo = mid + 1; else hi = mid; }
        lo_s = lo;
        int lo2 = lo, hi2 = M;
        while (lo2 < hi2) { int mid = (lo2 + hi2) >> 1; if (batch[mid] < g + 1) lo2 = mid + 1; else hi2 = mid; }
        hi_s = lo2;
    }
    __syncthreads();
    int lo = lo_s, hi = hi_s;
    int c2 = threadIdx.x & 63, quarter = threadIdx.x >> 6;
    float ax = 0.f, ay = 0.f;
    for (int i = lo + quarter; i < hi; i += 4) {
        float2 v = up2(*reinterpret_cast<const unsigned*>(Hf + (size_t)i * HDIM + c2 * 2));
        ax += v.x; ay += v.y;
    }
    smx[threadIdx.x] = ax; smy[threadIdx.x] = ay;
    __syncthreads();
    if (quarter == 0) {
        float sx = smx[c2] + smx[c2 + 64] + smx[c2 + 128] + smx[c2 + 192];
        float sy = smy[c2] + smy[c2 + 64] + smy[c2 + 128] + smy[c2 + 192];
        float cnt = (float)(hi - lo); if (cnt < 1.f) cnt = 1.f;
        pooled[g * HDIM + c2 * 2]     = fmaxf(sx / cnt, 0.f);
        pooled[g * HDIM + c2 * 2 + 1] = fmaxf(sy / cnt, 0.f);
    }
}

// ---------------- prediction head -------------------------------------------
__global__ void pred_kernel(const float* __restrict__ pa, const float* __restrict__ pv,
                            const float* __restrict__ pW, const float* __restrict__ pb,
                            float* __restrict__ out) {
    int g = blockIdx.x, lane = threadIdx.x; // 64 threads
    float s = pa[g * HDIM + lane] * pW[lane]
            + pa[g * HDIM + 64 + lane] * pW[64 + lane]
            + pv[g * HDIM + lane] * pW[HDIM + lane]
            + pv[g * HDIM + 64 + lane] * pW[192 + lane];
    for (int off = 32; off; off >>= 1) s += __shfl_down(s, off);
    if (lane == 0) out[g] = s + pb[0];
}

extern "C" void kernel_launch(void* const* d_in, const int* in_sizes, int n_in,
                              void* d_out, int out_size, void* d_ws, size_t ws_size,
                              hipStream_t stream) {
    const float* atom_x   = (const float*)d_in[0];
    const float* voro_x   = (const float*)d_in[1];
    const int*   atom_ei  = (const int*)d_in[2];
    const int*   voro_ei  = (const int*)d_in[3];
    const int*   batch    = (const int*)d_in[4];
    const float* W_at_in  = (const float*)d_in[5];
    const float* W_vo_in  = (const float*)d_in[6];
    const float* atom_W   = (const float*)d_in[7];
    const float* voro_W   = (const float*)d_in[8];
    const float* atom_Wih = (const float*)d_in[9];
    const float* atom_Whh = (const float*)d_in[10];
    const float* atom_bih = (const float*)d_in[11];
    const float* atom_bhh = (const float*)d_in[12];
    const float* voro_Wih = (const float*)d_in[13];
    const float* voro_Whh = (const float*)d_in[14];
    const float* voro_bih = (const float*)d_in[15];
    const float* voro_bhh = (const float*)d_in[16];
    const float* pred_W   = (const float*)d_in[17];
    const float* pred_b   = (const float*)d_in[18];
    float* out = (float*)d_out;

    const int Nn = in_sizes[4];
    const int Ee = in_sizes[2] / 2;
    const int Gg = out_size;
    const int Npad = (Nn + 31) & ~31;
    const int nbScan = (Nn + 1023) / 1024;

    char* base = (char*)d_ws;
    size_t off = 0;
    auto alloc = [&](size_t bytes) -> char* {
        char* p = base + off;
        off = (off + bytes + 255) & ~(size_t)255;
        return p;
    };

    u16 *HhA[2], *HhB[2];
    u16 *WfHi[2], *WfLo[2], *WhHi[2], *WhLo[2], *WnHi[2], *WnLo[2];
    int *row_off[2], *cursor[2], *ssrc[2], *bt[2];
    for (int t = 0; t < 2; ++t) {
        HhA[t] = (u16*)alloc((size_t)Npad * HDIM * 2);
        HhB[t] = (u16*)alloc((size_t)Npad * HDIM * 2);
        WfHi[t] = (u16*)alloc(4 * 49152 * 2); WfLo[t] = (u16*)alloc(4 * 49152 * 2);
        WhHi[t] = (u16*)alloc(384 * 128 * 2); WhLo[t] = (u16*)alloc(384 * 128 * 2);
        WnHi[t] = (u16*)alloc(128 * 64 * 2);  WnLo[t] = (u16*)alloc(128 * 64 * 2);
        row_off[t] = (int*)alloc((size_t)(Nn + 1) * 4);
        cursor[t]  = (int*)alloc((size_t)Nn * 4);
        ssrc[t]    = (int*)alloc((size_t)(Ee + 64) * 4);   // +64 pad for wave window reads
        bt[t]      = (int*)alloc((size_t)(nbScan + 1) * 4);
    }
    float* pooledA = (float*)alloc((size_t)Gg * HDIM * 4);
    float* pooledV = (float*)alloc((size_t)Gg * HDIM * 4);

    prep_wfull<<<dim3(192, 4, 2), 256, 0, stream>>>(atom_W, atom_Wih, voro_W, voro_Wih,
                                                    WfHi[0], WfLo[0], WfHi[1], WfLo[1]);
    prep_split2<<<dim3(192, 2), 256, 0, stream>>>(atom_Whh, voro_Whh,
                                                  WhHi[0], WhLo[0], WhHi[1], WhLo[1], 384 * 128);
    prep_win2<<<dim3(32, 2), 256, 0, stream>>>(W_at_in, W_vo_in,
                                               WnHi[0], WnLo[0], WnHi[1], WnLo[1]);

    const int eb  = (Ee + 255) / 256;
    const int nb  = (Nn + 255) / 256;
    const int gbs = Npad / 32;

    embed_k<<<dim3(gbs, 2), 256, 0, stream>>>(atom_x, voro_x,
                                              WnHi[0], WnLo[0], WnHi[1], WnLo[1],
                                              HhA[0], HhA[1], Nn);

    zero_int2<<<dim3(nb, 2), 256, 0, stream>>>(cursor[0], cursor[1], Nn);
    hist_k2<<<dim3(eb, 2), 256, 0, stream>>>(atom_ei + Ee, voro_ei + Ee, cursor[0], cursor[1], Ee);
    scan_part<<<dim3(nbScan, 2), 256, 0, stream>>>(cursor[0], cursor[1], row_off[0], row_off[1],
                                                   bt[0], bt[1], Nn);
    scan_tops<<<2, 64, 0, stream>>>(bt[0], bt[1], nbScan);
    scan_fix<<<dim3((Nn + 1 + 255) / 256, 2), 256, 0, stream>>>(row_off[0], row_off[1], bt[0], bt[1],
                                                                cursor[0], cursor[1], Nn, nbScan);
    scatter_k2<<<dim3(eb, 2), 256, 0, stream>>>(atom_ei, atom_ei + Ee, voro_ei, voro_ei + Ee,
                                                cursor[0], cursor[1], ssrc[0], ssrc[1], Ee);

    u16 *gA0 = HhA[0], *gB0 = HhB[0], *gA1 = HhA[1], *gB1 = HhB[1];
    for (int s = 0; s < 4; ++s) {
        step_k<<<dim3(gbs, 2), 512, 0, stream>>>(
            gA0, gA1, row_off[0], row_off[1], ssrc[0], ssrc[1],
            WfHi[0] + (size_t)s * 49152, WfLo[0] + (size_t)s * 49152,
            WfHi[1] + (size_t)s * 49152, WfLo[1] + (size_t)s * 49152,
            WhHi[0], WhLo[0], WhHi[1], WhLo[1],
            atom_bih, atom_bhh, voro_bih, voro_bhh,
            gB0, gB1, Nn);
        u16* up;
        up = gA0; gA0 = gB0; gB0 = up;
        up = gA1; gA1 = gB1; gB1 = up;
    }
    pool_k<<<dim3(Gg, 2), 256, 0, stream>>>(gA0, gA1, batch, pooledA, pooledV, Nn);
    pred_kernel<<<Gg, 64, 0, stream>>>(pooledA, pooledV, pred_W, pred_b, out);
}